// Round 1
// baseline (4397.665 us; speedup 1.0000x reference)
//
#include <hip/hip_runtime.h>
#include <math.h>

typedef long long ll;

// ---------------- constants ----------------
// b=2, D=256, n=3072, L=8, H=4, DH=64
#define NPOS 3072
#define NB 2

// workspace offsets (floats)
#define OFF_DQA  0LL
#define OFF_DQB  1572864LL
#define OFF_D3A  3145728LL
#define OFF_D3B  4718592LL
#define OFF_QKV  6291456LL
#define OFF_OBUF 11010048LL
#define OFF_YBUF 12582912LL
#define OFF_YBUF2 15728640LL
#define OFF_KVP  18874368LL
#define OFF_KSP  19660800LL
#define OFF_KV   19673088LL
#define OFF_KSUM 19705856LL
#define OFF_UVEC 19706368LL
#define OFF_E2   19708416LL
#define OFF_E3A  19757568LL
#define OFF_E3B  19763712LL
#define OFF_ATT  19769856LL
#define OFF_RMAX 19825152LL
#define OFF_RSUM 19831296LL
#define OFF_CMAX 19837440LL
#define OFF_CSUM 19843584LL
#define OFF_COLP 19849728LL   // pmax[2*8*3072] then psum[2*8*3072]
#define OFF_I0   19948032LL
#define OFF_M0   19951104LL
#define OFF_I1   19954176LL

__device__ __forceinline__ float waveSum(float v) {
#pragma unroll
  for (int off = 32; off > 0; off >>= 1) v += __shfl_down(v, off);
  return v;
}

// ------------------------------------------------------------------
// Generic fp32 GEMM: C[M,N] = act(alpha*(A@B) + bias + R)
// A: if ta==0  -> [M,K] row-major ; if ta==1 -> [K,M] row-major (ld = M)
// B: [K,N] row-major (ld = N). C: [M,N] (ld = N). batch via blockIdx.z.
// M%64==0, N%64==0, K%16==0 (guaranteed by problem shapes)
// ------------------------------------------------------------------
__global__ __launch_bounds__(256) void gemm_k(
    const float* __restrict__ A, const float* __restrict__ B,
    const float* __restrict__ bias, const float* __restrict__ R,
    float* __restrict__ C,
    int M, int N, int K, int ta, float alpha,
    ll aB, ll bB, ll rB, ll cB, int act)
{
  __shared__ float As[16][68];
  __shared__ float Bs[16][64];
  const int b = blockIdx.z;
  const float* Ab = A + (ll)b * aB;
  const float* Bb = B + (ll)b * bB;
  float* Cb = C + (ll)b * cB;
  const int n0 = blockIdx.x * 64, m0 = blockIdx.y * 64;
  const int t = threadIdx.x;
  const int tx = t & 15, ty = t >> 4;
  float acc[4][4] = {};
  for (int k0 = 0; k0 < K; k0 += 16) {
    if (ta) {
      int k = t >> 4, m4 = (t & 15) << 2;
      float4 v = *(const float4*)(Ab + (ll)(k0 + k) * M + m0 + m4);
      *(float4*)&As[k][m4] = v;
    } else {
      int m = t >> 2, k4 = (t & 3) << 2;
      float4 v = *(const float4*)(Ab + (ll)(m0 + m) * K + k0 + k4);
      As[k4 + 0][m] = v.x; As[k4 + 1][m] = v.y;
      As[k4 + 2][m] = v.z; As[k4 + 3][m] = v.w;
    }
    {
      int k = t >> 4, n4 = (t & 15) << 2;
      *(float4*)&Bs[k][n4] = *(const float4*)(Bb + (ll)(k0 + k) * N + n0 + n4);
    }
    __syncthreads();
#pragma unroll
    for (int kk = 0; kk < 16; ++kk) {
      float a[4], bb[4];
      *(float4*)a = *(const float4*)&As[kk][ty << 2];
      *(float4*)bb = *(const float4*)&Bs[kk][tx << 2];
#pragma unroll
      for (int i = 0; i < 4; ++i)
#pragma unroll
        for (int j = 0; j < 4; ++j)
          acc[i][j] = fmaf(a[i], bb[j], acc[i][j]);
    }
    __syncthreads();
  }
#pragma unroll
  for (int i = 0; i < 4; ++i) {
    int m = m0 + (ty << 2) + i;
    float bv = bias ? bias[m] : 0.f;
    ll rowoff = (ll)m * N + n0 + (tx << 2);
    float4 rv = make_float4(0.f, 0.f, 0.f, 0.f);
    if (R) rv = *(const float4*)(R + (ll)b * rB + rowoff);
    float* rp = &rv.x;
    float4 o;
    float* op = &o.x;
#pragma unroll
    for (int j = 0; j < 4; ++j) {
      float v = acc[i][j] * alpha + bv;
      if (R) v += rp[j];
      if (act == 1) v = v > 0.f ? v : (expf(v) - 1.f);  // elu
      op[j] = v;
    }
    *(float4*)(Cb + rowoff) = o;
  }
}

// ---------------- linear attention ----------------
// qkv: [b][768][3072], q rows 0..255 (c=dh*4+h), k rows 256.., v rows 512..
// kvp: partial KV [bh][24][qd*64+kd], ksp: partial ksum [bh][24][64]
__global__ __launch_bounds__(256) void kv_partial_k(
    const float* __restrict__ qkv, float* __restrict__ kvp, float* __restrict__ ksp)
{
  __shared__ float ks[64][33];
  __shared__ float vs[64][33];
  const int p = blockIdx.x, h = blockIdx.y, b = blockIdx.z;
  const float* base = qkv + (ll)b * 2359296;
  const int t = threadIdx.x;
  const int tq = (t >> 4) << 2;
  const int tk = (t & 15) << 2;
  float acc[4][4] = {};
  float ksl = 0.f;
  const int col = t & 31, r0 = t >> 5;
  for (int sub = 0; sub < 4; ++sub) {
    const int m0 = p * 128 + sub * 32;
#pragma unroll
    for (int i = 0; i < 8; ++i) {
      int d = r0 * 8 + i;
      float kvv = base[(ll)(256 + d * 4 + h) * NPOS + m0 + col];
      ks[d][col] = kvv > 0.f ? kvv + 1.f : expf(kvv);  // elu(x)+1
      vs[d][col] = base[(ll)(512 + d * 4 + h) * NPOS + m0 + col];
    }
    __syncthreads();
#pragma unroll 8
    for (int mm = 0; mm < 32; ++mm) {
      float kk4[4], vv4[4];
#pragma unroll
      for (int i = 0; i < 4; ++i) { kk4[i] = ks[tk + i][mm]; vv4[i] = vs[tq + i][mm]; }
#pragma unroll
      for (int i = 0; i < 4; ++i)
#pragma unroll
        for (int j = 0; j < 4; ++j)
          acc[i][j] = fmaf(vv4[i], kk4[j], acc[i][j]);
    }
    if (t < 64) {
#pragma unroll 8
      for (int mm = 0; mm < 32; ++mm) ksl += ks[t][mm];
    }
    __syncthreads();
  }
  ll o = (((ll)(b * 4 + h)) * 24 + p) * 4096;
#pragma unroll
  for (int i = 0; i < 4; ++i) {
    float4 v; v.x = acc[i][0]; v.y = acc[i][1]; v.z = acc[i][2]; v.w = acc[i][3];
    *(float4*)(kvp + o + (tq + i) * 64 + tk) = v;
  }
  if (t < 64) ksp[((b * 4 + h) * 24 + p) * 64 + t] = ksl;
}

// kv output stored TRANSPOSED: kv[bh][d*64+qd]
__global__ void kv_reduce_k(const float* __restrict__ kvp, const float* __restrict__ ksp,
                            float* __restrict__ kv, float* __restrict__ ksum)
{
  int bh = blockIdx.x; int t = threadIdx.x;
  for (int e = t; e < 4096; e += 256) {
    float s = 0.f;
    for (int p = 0; p < 24; ++p) s += kvp[((ll)bh * 24 + p) * 4096 + e];
    kv[(ll)bh * 4096 + (ll)(e & 63) * 64 + (e >> 6)] = s;   // [d][qd]
  }
  if (t < 64) {
    float s = 0.f;
    for (int p = 0; p < 24; ++p) s += ksp[((ll)bh * 24 + p) * 64 + t];
    ksum[bh * 64 + t] = s;
  }
}

// out[qd,n] = z[n] * sum_d KV[qd][d] * qhat[d][n]
__global__ __launch_bounds__(256) void attn_out_k(
    const float* __restrict__ qkv, const float* __restrict__ kv,
    const float* __restrict__ ksum, float* __restrict__ obuf)
{
  __shared__ float qt[64][64];     // [d][nl]
  __shared__ float kvT[64][68];    // [d][qd]
  __shared__ float zs[64];
  __shared__ float kss[64];
  const int n0 = blockIdx.x * 64, h = blockIdx.y, b = blockIdx.z;
  const float* qb = qkv + (ll)b * 2359296;
  const int t = threadIdx.x;
  {
    int nl = t & 63; int dg = t >> 6;
#pragma unroll
    for (int i = 0; i < 16; ++i) {
      int d = dg * 16 + i;
      float q = qb[(ll)(d * 4 + h) * NPOS + n0 + nl];
      qt[d][nl] = q > 0.f ? q + 1.f : expf(q);  // elu+1
    }
  }
  {
    const float* kvb = kv + (ll)(b * 4 + h) * 4096;
#pragma unroll
    for (int i = 0; i < 16; ++i) {
      int idx = t + i * 256;
      kvT[idx >> 6][idx & 63] = kvb[idx];
    }
  }
  if (t < 64) kss[t] = ksum[(b * 4 + h) * 64 + t];
  __syncthreads();
  if (t < 64) {
    float s = 0.f;
    for (int d = 0; d < 64; ++d) s = fmaf(qt[d][t], kss[d], s);
    zs[t] = 1.f / (s + 1e-6f);
  }
  __syncthreads();
  const int tx = t & 15, ty = t >> 4;
  float acc[4][4] = {};
  for (int d = 0; d < 64; ++d) {
    float a[4], bb[4];
#pragma unroll
    for (int i = 0; i < 4; ++i) a[i] = kvT[d][(ty << 2) + i];
    *(float4*)bb = *(const float4*)&qt[d][tx << 2];
#pragma unroll
    for (int i = 0; i < 4; ++i)
#pragma unroll
      for (int j = 0; j < 4; ++j)
        acc[i][j] = fmaf(a[i], bb[j], acc[i][j]);
  }
  float z4[4];
#pragma unroll
  for (int j = 0; j < 4; ++j) z4[j] = zs[(tx << 2) + j];
#pragma unroll
  for (int i = 0; i < 4; ++i) {
    int qd = (ty << 2) + i;
    float* orow = obuf + (ll)b * 786432 + (ll)(qd * 4 + h) * NPOS + n0;
    float4 o;
    o.x = acc[i][0] * z4[0]; o.y = acc[i][1] * z4[1];
    o.z = acc[i][2] * z4[2]; o.w = acc[i][3] * z4[3];
    *(float4*)(orow + (tx << 2)) = o;
  }
}

// ---------------- instnorm (+relu) in place, rows of 3072 ----------------
__global__ __launch_bounds__(256) void instnorm_relu_k(float* __restrict__ y)
{
  const ll row = ((ll)blockIdx.y * 512 + blockIdx.x) * NPOS;
  const int t = threadIdx.x;
  __shared__ float red[4];
  float s = 0.f;
  for (int n = t; n < NPOS; n += 256) s += y[row + n];
  s = waveSum(s);
  if ((t & 63) == 0) red[t >> 6] = s;
  __syncthreads();
  float mu = (red[0] + red[1] + red[2] + red[3]) * (1.f / NPOS);
  __syncthreads();
  float vs = 0.f;
  for (int n = t; n < NPOS; n += 256) { float d = y[row + n] - mu; vs = fmaf(d, d, vs); }
  vs = waveSum(vs);
  if ((t & 63) == 0) red[t >> 6] = vs;
  __syncthreads();
  float var = (red[0] + red[1] + red[2] + red[3]) * (1.f / NPOS);
  float rs = rsqrtf(var + 1e-5f);
  for (int n = t; n < NPOS; n += 256) {
    float v = (y[row + n] - mu) * rs;
    y[row + n] = v > 0.f ? v : 0.f;
  }
}

// copy x [2][256][3072] into ybuf rows 0..255 (ybuf is [2][512][3072])
__global__ void copy_xy_k(const float* __restrict__ x, float* __restrict__ yb)
{
  ll gi = (ll)blockIdx.x * 256 + threadIdx.x;
  ll e4 = gi * 4;
  int b = (int)(e4 / 786432);
  ll r = e4 - (ll)b * 786432;
  *(float4*)(yb + (ll)b * 1572864 + r) = *(const float4*)(x + e4);
}

// ---------------- GAT ----------------
__global__ void gat_prep_k(const float* __restrict__ gatW, const float* __restrict__ gata,
                           float* __restrict__ uvec)
{
  int gi = blockIdx.x; int d = threadIdx.x;
  const float* W = gatW + (ll)gi * 65536;
  const float* a = gata + gi * 512;
  float u0 = 0.f, u1 = 0.f;
  for (int o = 0; o < 256; ++o) {
    float w = W[d * 256 + o];
    u0 = fmaf(w, a[o], u0);
    u1 = fmaf(w, a[256 + o], u1);
  }
  uvec[gi * 512 + d] = u0;
  uvec[gi * 512 + 256 + d] = u1;
}

__global__ void gat_edot3_k(const float* __restrict__ x, const float* __restrict__ u,
                            float* __restrict__ e3a, float* __restrict__ e3b)
{
  int n = blockIdx.x * 256 + threadIdx.x; int b = blockIdx.y;
  const float* xb = x + (ll)b * 786432;
  float a0 = 0.f, a1 = 0.f;
  for (int d = 0; d < 256; ++d) {
    float v = xb[(ll)d * NPOS + n];
    a0 = fmaf(v, u[d], a0);
    a1 = fmaf(v, u[256 + d], a1);
  }
  e3a[b * NPOS + n] = a0; e3b[b * NPOS + n] = a1;
}

__global__ void gat_edot2_k(const float* __restrict__ x, const float* __restrict__ u1,
                            float* __restrict__ e2)
{
  int m = blockIdx.x * 256 + threadIdx.x; int b = blockIdx.y;
  const float* xb = x + (ll)b * 6291456;
  float a = 0.f;
  for (int d = 0; d < 256; ++d) a = fmaf(xb[(ll)d * 24576 + m], u1[d], a);
  e2[b * 24576 + m] = a;
}

__global__ void gat_att_k(const float* __restrict__ e3a, const float* __restrict__ e3b,
                          const float* __restrict__ e2, float* __restrict__ att)
{
  int n = blockIdx.x * 256 + threadIdx.x; int b = blockIdx.y;
  float ea = e3a[b * NPOS + n], eb = e3b[b * NPOS + n];
  float e[9];
  e[0] = ea + eb;
  const float* e2b = e2 + (ll)b * 24576 + (ll)n * 8;
#pragma unroll
  for (int l = 0; l < 8; ++l) e[l + 1] = ea + e2b[l];
  float mx = -3.4e38f;
#pragma unroll
  for (int l = 0; l < 9; ++l) {
    e[l] = e[l] >= 0.f ? e[l] : 0.2f * e[l];  // leaky_relu 0.2
    mx = fmaxf(mx, e[l]);
  }
  float s = 0.f;
#pragma unroll
  for (int l = 0; l < 9; ++l) { e[l] = expf(e[l] - mx); s += e[l]; }
  float inv = 1.f / s;
  float* ao = att + ((ll)b * NPOS + n) * 9;
#pragma unroll
  for (int l = 0; l < 9; ++l) ao[l] = e[l] * inv;
}

__global__ void gat_g_k(const float* __restrict__ d3, const float* __restrict__ d2db,
                        const float* __restrict__ att, float* __restrict__ g)
{
  int n = blockIdx.x * 256 + threadIdx.x;
  int d = blockIdx.y; int b = blockIdx.z;
  const float* at = att + ((ll)b * NPOS + n) * 9;
  float s = at[0] * d3[((ll)b * 256 + d) * NPOS + n];
  const float* row = d2db + ((ll)b * 256 + d) * 24576 + (ll)n * 8;
#pragma unroll
  for (int l = 0; l < 8; ++l) s = fmaf(at[l + 1], row[l], s);
  g[((ll)b * 256 + d) * NPOS + n] = s;
}

// ---------------- final: normalize / softmax / matching ----------------
__global__ void norm_scale_k(float* __restrict__ v)
{
  int n = blockIdx.x * 256 + threadIdx.x;
  ll base = (ll)blockIdx.y * 786432 + n;
  float s = 0.f;
  for (int c = 0; c < 256; ++c) { float x = v[base + (ll)c * NPOS]; s = fmaf(x, x, s); }
  float sc = 1.f / fmaxf(sqrtf(s), 1e-12f);
  for (int c = 0; c < 256; ++c) v[base + (ll)c * NPOS] *= sc;
}

__global__ __launch_bounds__(256) void row_stats_k(const float* __restrict__ S,
                                                   float* __restrict__ rmax, float* __restrict__ rsum)
{
  int n = blockIdx.x; int b = blockIdx.y;
  const float* row = S + (ll)b * 9437184 + (ll)n * NPOS;
  int t = threadIdx.x;
  __shared__ float red[4];
  float mx = -3.4e38f;
  for (int m = t; m < NPOS; m += 256) mx = fmaxf(mx, row[m]);
#pragma unroll
  for (int off = 32; off > 0; off >>= 1) mx = fmaxf(mx, __shfl_down(mx, off));
  if ((t & 63) == 0) red[t >> 6] = mx;
  __syncthreads();
  mx = fmaxf(fmaxf(red[0], red[1]), fmaxf(red[2], red[3]));
  __syncthreads();
  float s = 0.f;
  for (int m = t; m < NPOS; m += 256) s += expf(row[m] - mx);
  s = waveSum(s);
  if ((t & 63) == 0) red[t >> 6] = s;
  __syncthreads();
  if (t == 0) {
    rmax[b * NPOS + n] = mx;
    rsum[b * NPOS + n] = red[0] + red[1] + red[2] + red[3];
  }
}

__global__ void colstat_part_k(const float* __restrict__ S,
                               float* __restrict__ pmax, float* __restrict__ psum)
{
  int m = blockIdx.x * 256 + threadIdx.x;
  int chunk = blockIdx.y; int b = blockIdx.z;
  const float* base = S + (ll)b * 9437184 + m;
  float mx = -3.4e38f, s = 0.f;
  int n0 = chunk * 384;
  for (int n = n0; n < n0 + 384; ++n) {
    float v = base[(ll)n * NPOS];
    if (v > mx) { s = s * expf(mx - v) + 1.f; mx = v; }
    else s += expf(v - mx);
  }
  ll o = ((ll)b * 8 + chunk) * NPOS + m;
  pmax[o] = mx; psum[o] = s;
}

__global__ void colstat_comb_k(const float* __restrict__ pmax, const float* __restrict__ psum,
                               float* __restrict__ cmax, float* __restrict__ csum)
{
  int m = blockIdx.x * 256 + threadIdx.x; int b = blockIdx.y;
  float M = -3.4e38f;
  for (int c = 0; c < 8; ++c) M = fmaxf(M, pmax[((ll)b * 8 + c) * NPOS + m]);
  float s = 0.f;
  for (int c = 0; c < 8; ++c)
    s += psum[((ll)b * 8 + c) * NPOS + m] * expf(pmax[((ll)b * 8 + c) * NPOS + m] - M);
  cmax[b * NPOS + m] = M; csum[b * NPOS + m] = s;
}

__global__ void conf_fix_k(float* __restrict__ S, const float* __restrict__ rmax,
                           const float* __restrict__ rsum, const float* __restrict__ cmax,
                           const float* __restrict__ csum)
{
  ll gi = ((ll)blockIdx.x * 256 + threadIdx.x) * 4;
  int b = (int)(gi / 9437184);
  ll r = gi - (ll)b * 9437184;
  int n = (int)(r / NPOS);
  int m = (int)(r - (ll)n * NPOS);
  float4 v = *(float4*)(S + gi);
  float rm = rmax[b * NPOS + n];
  float irs = 1.f / rsum[b * NPOS + n];
  float* vp = &v.x;
#pragma unroll
  for (int j = 0; j < 4; ++j) {
    float cm = cmax[b * NPOS + m + j];
    float ics = 1.f / csum[b * NPOS + m + j];
    vp[j] = expf(vp[j] - rm) * irs * expf(vp[j] - cm) * ics;
  }
  *(float4*)(S + gi) = v;
}

__global__ __launch_bounds__(256) void argmax_row_k(const float* __restrict__ Cf,
                                                    int* __restrict__ i0, float* __restrict__ m0)
{
  int n = blockIdx.x;
  const float* row = Cf + (ll)n * NPOS;
  int t = threadIdx.x;
  float bv = -1.f; int bi = 0x7fffffff;
  for (int m = t; m < NPOS; m += 256) {
    float v = row[m];
    if (v > bv) { bv = v; bi = m; }
  }
#pragma unroll
  for (int off = 32; off > 0; off >>= 1) {
    float ov = __shfl_down(bv, off);
    int oi = __shfl_down(bi, off);
    if (ov > bv || (ov == bv && oi < bi)) { bv = ov; bi = oi; }
  }
  __shared__ float rv[4]; __shared__ int ri[4];
  if ((t & 63) == 0) { rv[t >> 6] = bv; ri[t >> 6] = bi; }
  __syncthreads();
  if (t == 0) {
    for (int w = 1; w < 4; ++w)
      if (rv[w] > bv || (rv[w] == bv && ri[w] < bi)) { bv = rv[w]; bi = ri[w]; }
    i0[n] = bi; m0[n] = bv;
  }
}

__global__ void argmax_col_k(const float* __restrict__ Cf, int* __restrict__ i1)
{
  int m = blockIdx.x * 256 + threadIdx.x;
  float bv = -1.f; int bi = 0;
  for (int n = 0; n < NPOS; ++n) {
    float v = Cf[(ll)n * NPOS + m];
    if (v > bv) { bv = v; bi = n; }
  }
  i1[m] = bi;
}

__global__ void match0_k(const int* __restrict__ i0, const float* __restrict__ m0,
                         const int* __restrict__ i1, float* __restrict__ out)
{
  int n = blockIdx.x * 256 + threadIdx.x;
  int j = i0[n];
  bool mut = (i1[j] == n);
  float ms0 = mut ? m0[n] : 0.f;
  bool valid = mut && (ms0 > 0.2f);
  out[n] = valid ? (float)j : -1.f;
  out[6144 + n] = ms0;
}

__global__ void match1_k(const int* __restrict__ i0, const int* __restrict__ i1,
                         float* __restrict__ out)
{
  int m = blockIdx.x * 256 + threadIdx.x;
  int j = i1[m];
  bool mut = (i0[j] == m);
  float ms0v = out[6144 + j];
  float ind0v = out[j];
  float ms1 = mut ? ms0v : 0.f;
  bool valid1 = mut && (ind0v >= 0.f);
  out[3072 + m] = valid1 ? (float)j : -1.f;
  out[9216 + m] = ms1;
}

// ------------------------------------------------------------------
extern "C" void kernel_launch(void* const* d_in, const int* in_sizes, int n_in,
                              void* d_out, int out_size, void* d_ws, size_t ws_size,
                              hipStream_t stream)
{
  const float* desc2dq = (const float*)d_in[0];
  const float* desc3db = (const float*)d_in[1];
  const float* desc2db = (const float*)d_in[2];
  const float* projw = (const float*)d_in[3];
  const float* projb = (const float*)d_in[4];
  const float* mergew = (const float*)d_in[5];
  const float* mergeb = (const float*)d_in[6];
  const float* mlp1w = (const float*)d_in[7];
  const float* mlp1b = (const float*)d_in[8];
  const float* mlp2w = (const float*)d_in[9];
  const float* mlp2b = (const float*)d_in[10];
  const float* gatW = (const float*)d_in[11];
  const float* gata = (const float*)d_in[12];
  const float* finw = (const float*)d_in[13];
  const float* finb = (const float*)d_in[14];

  float* ws = (float*)d_ws;
  float* out = (float*)d_out;

  float* dq  = ws + OFF_DQA;
  float* dq2 = ws + OFF_DQB;
  float* d3  = ws + OFF_D3A;
  float* d32 = ws + OFF_D3B;
  float* qkv = ws + OFF_QKV;
  float* obuf = ws + OFF_OBUF;
  float* ybuf = ws + OFF_YBUF;
  float* ybuf2 = ws + OFF_YBUF2;
  float* kvp = ws + OFF_KVP;
  float* ksp = ws + OFF_KSP;
  float* kvb = ws + OFF_KV;
  float* ksum = ws + OFF_KSUM;
  float* uvec = ws + OFF_UVEC;
  float* e2 = ws + OFF_E2;
  float* e3a = ws + OFF_E3A;
  float* e3b = ws + OFF_E3B;
  float* att = ws + OFF_ATT;
  float* rmax = ws + OFF_RMAX;
  float* rsum = ws + OFF_RSUM;
  float* cmax = ws + OFF_CMAX;
  float* csum = ws + OFF_CSUM;
  float* pmax = ws + OFF_COLP;
  float* psum = ws + OFF_COLP + 49152;
  int* i0 = (int*)(ws + OFF_I0);
  float* m0 = ws + OFF_M0;
  int* i1 = (int*)(ws + OFF_I1);

  auto gemm = [&](const float* A, const float* B, const float* bias, const float* R,
                  float* C, int M, int N, int K, int ta, float alpha,
                  ll aB, ll bB, ll rB, ll cB, int act) {
    gemm_k<<<dim3(N / 64, M / 64, NB), 256, 0, stream>>>(
        A, B, bias, R, C, M, N, K, ta, alpha, aB, bB, rB, cB, act);
  };

  // init state
  hipMemcpyAsync(dq, desc2dq, (size_t)1572864 * 4, hipMemcpyDeviceToDevice, stream);
  hipMemcpyAsync(d3, desc3db, (size_t)1572864 * 4, hipMemcpyDeviceToDevice, stream);
  gat_prep_k<<<4, 256, 0, stream>>>(gatW, gata, uvec);

  auto attn_prop = [&](const float* x, const float* src, float* xo, int ai) {
    const float* pw = projw + (ll)ai * 3 * 65536;
    const float* pb = projb + (ll)ai * 768;
    // q projection (M=256) and fused k|v projection (M=512)
    gemm(pw, x, pb, nullptr, qkv, 256, NPOS, 256, 0, 1.f, 0, 786432, 0, 2359296, 0);
    gemm(pw + 65536, src, pb + 256, nullptr, qkv + 786432, 512, NPOS, 256, 0, 1.f,
         0, 786432, 0, 2359296, 0);
    kv_partial_k<<<dim3(24, 4, NB), 256, 0, stream>>>(qkv, kvp, ksp);
    kv_reduce_k<<<8, 256, 0, stream>>>(kvp, ksp, kvb, ksum);
    attn_out_k<<<dim3(48, 4, NB), 256, 0, stream>>>(qkv, kvb, ksum, obuf);
    // merge into ybuf rows 256..511
    gemm(mergew + (ll)ai * 65536, obuf, mergeb + (ll)ai * 256, nullptr, ybuf + 786432,
         256, NPOS, 256, 0, 1.f, 0, 786432, 0, 1572864, 0);
    copy_xy_k<<<1536, 256, 0, stream>>>(x, ybuf);
    gemm(mlp1w + (ll)ai * 262144, ybuf, mlp1b + (ll)ai * 512, nullptr, ybuf2,
         512, NPOS, 512, 0, 1.f, 0, 1572864, 0, 1572864, 0);
    instnorm_relu_k<<<dim3(512, NB), 256, 0, stream>>>(ybuf2);
    gemm(mlp2w + (ll)ai * 131072, ybuf2, mlp2b + (ll)ai * 256, x, xo,
         256, NPOS, 512, 0, 1.f, 0, 1572864, 786432, 786432, 0);
  };

  auto gat_layer = [&](const float* din, float* dout, int gi) {
    const float* uv = uvec + gi * 512;
    gat_edot3_k<<<dim3(12, NB), 256, 0, stream>>>(din, uv, e3a, e3b);
    gat_edot2_k<<<dim3(96, NB), 256, 0, stream>>>(desc2db, uv + 256, e2);
    gat_att_k<<<dim3(12, NB), 256, 0, stream>>>(e3a, e3b, e2, att);
    gat_g_k<<<dim3(12, 256, NB), 256, 0, stream>>>(din, desc2db, att, obuf);
    // h = W^T @ g, elu  (ta=1: A is [K=256(d)][M=256(o)] with ld=M)
    gemm(gatW + (ll)gi * 65536, obuf, nullptr, nullptr, dout,
         256, NPOS, 256, 1, 1.f, 0, 786432, 0, 786432, 1);
  };

  int ai = 0, gi = 0;
  for (int r = 0; r < 4; ++r) {
    // GATs (updates d3 only)
    gat_layer(d3, d32, gi);
    { float* tmp = d3; d3 = d32; d32 = tmp; }
    gi++;
    // self
    attn_prop(dq, dq, dq2, ai);
    attn_prop(d3, d3, d32, ai);
    { float* tmp = dq; dq = dq2; dq2 = tmp; }
    { float* tmp = d3; d3 = d32; d32 = tmp; }
    ai++;
    // cross (d3's update must use OLD dq)
    attn_prop(dq, d3, dq2, ai);
    attn_prop(d3, dq, d32, ai);
    { float* tmp = dq; dq = dq2; dq2 = tmp; }
    { float* tmp = d3; d3 = d32; d32 = tmp; }
    ai++;
  }

  // final projection + L2 normalize
  float* mq = ybuf;
  float* md = ybuf2;
  gemm(finw, dq, finb, nullptr, mq, 256, NPOS, 256, 0, 1.f, 0, 786432, 0, 786432, 0);
  gemm(finw, d3, finb, nullptr, md, 256, NPOS, 256, 0, 1.f, 0, 786432, 0, 786432, 0);
  norm_scale_k<<<dim3(12, NB), 256, 0, stream>>>(mq);
  norm_scale_k<<<dim3(12, NB), 256, 0, stream>>>(md);

  // scores = 10 * mq^T md  -> conf region of d_out
  float* conf = out + 12288;
  gemm(mq, md, nullptr, nullptr, conf, NPOS, NPOS, 256, 1, 10.f,
       786432, 786432, 0, 9437184, 0);

  row_stats_k<<<dim3(NPOS, NB), 256, 0, stream>>>(conf, rmax, rsum);
  colstat_part_k<<<dim3(12, 8, NB), 256, 0, stream>>>(conf, pmax, psum);
  colstat_comb_k<<<dim3(12, NB), 256, 0, stream>>>(pmax, psum, cmax, csum);
  conf_fix_k<<<18432, 256, 0, stream>>>(conf, rmax, rsum, cmax, csum);

  argmax_row_k<<<NPOS, 256, 0, stream>>>(conf, i0, m0);
  argmax_col_k<<<12, 256, 0, stream>>>(conf, i1);
  match0_k<<<12, 256, 0, stream>>>(i0, m0, i1, out);
  match1_k<<<12, 256, 0, stream>>>(i0, i1, out);
}

// Round 2
// 3831.789 us; speedup vs baseline: 1.1477x; 1.1477x over previous
//
#include <hip/hip_runtime.h>
#include <hip/hip_bf16.h>
#include <math.h>

typedef long long ll;
typedef __attribute__((ext_vector_type(8))) short s8v;
typedef __attribute__((ext_vector_type(4))) float f4v;

#define NPOS 3072
#define NB 2

// ---------------- workspace offsets (in floats) ----------------
#define OFF_DQA   0LL
#define OFF_DQB   1572864LL
#define OFF_D3A   3145728LL
#define OFF_D3B   4718592LL
#define OFF_DQABF 6291456LL
#define OFF_DQBBF 7077888LL
#define OFF_D3ABF 7864320LL
#define OFF_D3BBF 8650752LL
#define OFF_QKV   9437184LL     /* bf16 qkv 2x768x3072 shorts; md fp32 alias later */
#define OFF_OBUF  11796480LL    /* bf16 obuf 2x256x3072 shorts */
#define OFF_YBUF  12582912LL    /* bf16 ybuf 2x512x3072 shorts; mq_bf/md_bf alias later */
#define OFF_YBUF2 14155776LL    /* bf16 ybuf2 2x512x3072 shorts; kvp alias; mq fp32 alias */
#define OFF_WBF   15728640LL    /* bf16 weights, 5,570,560 shorts */
#define OFF_KV    18513920LL    /* kv 32768 + ksum 512 */
#define OFF_KSP   18547200LL
#define OFF_UVEC  18559488LL
#define OFF_E2    18561536LL
#define OFF_E3A   18610688LL
#define OFF_E3B   18616832LL
#define OFF_ATT   18622976LL
#define OFF_RMAX  18678272LL
#define OFF_RSUM  18684416LL
#define OFF_CMAX  18690560LL
#define OFF_CSUM  18696704LL
#define OFF_COLP  18702848LL
#define OFF_I0    18801152LL
#define OFF_M0    18804224LL
#define OFF_I1    18807296LL

__device__ __forceinline__ float b2f(short s) {
  union { unsigned u; float f; } c;
  c.u = ((unsigned)(unsigned short)s) << 16;
  return c.f;
}
__device__ __forceinline__ short f2b(float f) {
  __hip_bfloat16 h = __float2bfloat16(f);
  union { __hip_bfloat16 h; short s; } c; c.h = h; return c.s;
}
__device__ __forceinline__ unsigned pk2(float a, float b) {
  return (unsigned)(unsigned short)f2b(a) | ((unsigned)(unsigned short)f2b(b) << 16);
}

__device__ __forceinline__ float waveSum(float v) {
#pragma unroll
  for (int off = 32; off > 0; off >>= 1) v += __shfl_down(v, off);
  return v;
}

// ------------------------------------------------------------------
// bf16 MFMA GEMM: C[M,N] = act(alpha*(A@B) + bias + R)
// A bf16: ta=0 -> [M,K] row-major; ta=1 -> [K,M] row-major.
// B bf16: [K,N] row-major. C fp32 (optional), C2 bf16 (optional).
// M%128==0, N%128==0, K%32==0. batch via blockIdx.z.
// Block 256 thr = 4 waves; tile 128x128; wave 64x64 via 4x4 of 16x16x32.
// LDS: As[m][k] / Bs[n][k], stride 40 shorts (80B: 16B-aligned rows,
// <=2-way bank aliasing on ds_read_b128 - free per m136).
// ------------------------------------------------------------------
__global__ __launch_bounds__(256) void bgemm_k(
    const short* __restrict__ A, const short* __restrict__ B,
    const float* __restrict__ bias, const float* __restrict__ R,
    float* __restrict__ C, short* __restrict__ C2,
    int M, int N, int K, int ta, float alpha,
    ll aB, ll bB, ll rB, ll cB, ll c2B, int act)
{
  __shared__ __align__(16) short As[128 * 40];
  __shared__ __align__(16) short Bs[128 * 40];
  const int b = blockIdx.z;
  const short* Ab = A + (ll)b * aB;
  const short* Bb = B + (ll)b * bB;
  const int n0 = blockIdx.x * 128, m0 = blockIdx.y * 128;
  const int t = threadIdx.x;
  const int lane = t & 63, w = t >> 6;
  const int wm = (w & 1) * 64, wn = (w >> 1) * 64;
  const int fr = lane & 15;         // fragment row (A) / col (B)
  const int k8 = (lane >> 4) * 8;   // fragment k offset
  const int lda = ta ? M : K;

  f4v acc[4][4];
#pragma unroll
  for (int i = 0; i < 4; ++i)
#pragma unroll
    for (int j = 0; j < 4; ++j) acc[i][j] = (f4v)0.f;

  for (int k0 = 0; k0 < K; k0 += 32) {
    // ---- stage A into As[m][k] ----
    if (ta == 0) {
#pragma unroll
      for (int i = 0; i < 2; ++i) {
        int c = t + i * 256;               // 512 chunks of 8 shorts
        int m = c >> 2, kq = (c & 3) * 8;
        uint4 v = *(const uint4*)(Ab + (ll)(m0 + m) * lda + k0 + kq);
        *(uint4*)(As + m * 40 + kq) = v;
      }
    } else {
#pragma unroll
      for (int i = 0; i < 2; ++i) {
        int c = t + i * 256;               // 512 pair-chunks (2k x 4m)
        int kp = c & 15, mq = (c >> 4) * 4;
        const short* p0 = Ab + (ll)(k0 + kp * 2) * lda + m0 + mq;
        uint2 r0 = *(const uint2*)p0;
        uint2 r1 = *(const uint2*)(p0 + lda);
        unsigned s0[4] = { r0.x & 0xffffu, r0.x >> 16, r0.y & 0xffffu, r0.y >> 16 };
        unsigned s1[4] = { r1.x & 0xffffu, r1.x >> 16, r1.y & 0xffffu, r1.y >> 16 };
#pragma unroll
        for (int j = 0; j < 4; ++j)
          *(unsigned*)(As + (mq + j) * 40 + kp * 2) = s0[j] | (s1[j] << 16);
      }
    }
    // ---- stage B into Bs[n][k] (transposed pairs) ----
#pragma unroll
    for (int i = 0; i < 2; ++i) {
      int c = t + i * 256;
      int kp = c & 15, nq = (c >> 4) * 4;
      const short* p0 = Bb + (ll)(k0 + kp * 2) * N + n0 + nq;
      uint2 r0 = *(const uint2*)p0;
      uint2 r1 = *(const uint2*)(p0 + N);
      unsigned s0[4] = { r0.x & 0xffffu, r0.x >> 16, r0.y & 0xffffu, r0.y >> 16 };
      unsigned s1[4] = { r1.x & 0xffffu, r1.x >> 16, r1.y & 0xffffu, r1.y >> 16 };
#pragma unroll
      for (int j = 0; j < 4; ++j)
        *(unsigned*)(Bs + (nq + j) * 40 + kp * 2) = s0[j] | (s1[j] << 16);
    }
    __syncthreads();
    s8v af[4], bfr[4];
#pragma unroll
    for (int im = 0; im < 4; ++im)
      af[im] = *(const s8v*)(As + (wm + im * 16 + fr) * 40 + k8);
#pragma unroll
    for (int in = 0; in < 4; ++in)
      bfr[in] = *(const s8v*)(Bs + (wn + in * 16 + fr) * 40 + k8);
#pragma unroll
    for (int im = 0; im < 4; ++im)
#pragma unroll
      for (int in = 0; in < 4; ++in)
        acc[im][in] = __builtin_amdgcn_mfma_f32_16x16x32_bf16(
            af[im], bfr[in], acc[im][in], 0, 0, 0);
    __syncthreads();
  }

  const int q4 = (lane >> 4) * 4;
#pragma unroll
  for (int im = 0; im < 4; ++im) {
#pragma unroll
    for (int r = 0; r < 4; ++r) {
      int m = m0 + wm + im * 16 + q4 + r;
      float bv = bias ? bias[m] : 0.f;
#pragma unroll
      for (int in = 0; in < 4; ++in) {
        int n = n0 + wn + in * 16 + fr;
        float v = acc[im][in][r] * alpha + bv;
        ll off = (ll)m * N + n;
        if (R) v += R[(ll)b * rB + off];
        if (act) v = v > 0.f ? v : (expf(v) - 1.f);
        if (C) C[(ll)b * cB + off] = v;
        if (C2) C2[(ll)b * c2B + off] = f2b(v);
      }
    }
  }
}

// ---------------- fp32 -> bf16 conversion ----------------
__global__ void f2b_k(const float* __restrict__ src, short* __restrict__ dst, int n8)
{
  int gi = blockIdx.x * 256 + threadIdx.x;
  if (gi >= n8) return;
  ll e = (ll)gi * 8;
  float4 a = *(const float4*)(src + e);
  float4 b = *(const float4*)(src + e + 4);
  uint4 o;
  o.x = pk2(a.x, a.y); o.y = pk2(a.z, a.w);
  o.z = pk2(b.x, b.y); o.w = pk2(b.z, b.w);
  *(uint4*)(dst + e) = o;
}

// copy x fp32 [2][256][3072] -> ybuf_bf rows 0..255 ([2][512][3072] shorts)
__global__ void xcopy_k(const float* __restrict__ x, short* __restrict__ yb)
{
  int gi = blockIdx.x * 256 + threadIdx.x;  // 196608 threads
  ll e = (ll)gi * 8;
  int b = (int)(e / 786432);
  ll r = e - (ll)b * 786432;
  const float* p = x + (ll)b * 786432 + r;
  float4 a = *(const float4*)p;
  float4 c = *(const float4*)(p + 4);
  uint4 o;
  o.x = pk2(a.x, a.y); o.y = pk2(a.z, a.w);
  o.z = pk2(c.x, c.y); o.w = pk2(c.z, c.w);
  *(uint4*)(yb + (ll)b * 1572864 + r) = o;
}

// ---------------- linear attention (bf16 qkv) ----------------
// qkv: shorts [b][768][3072]; q rows 0..255 (c=dh*4+h), k 256.., v 512..
__global__ __launch_bounds__(256) void kv_partial_k(
    const short* __restrict__ qkv, float* __restrict__ kvp, float* __restrict__ ksp)
{
  __shared__ float ks[64][33];
  __shared__ float vs[64][33];
  const int p = blockIdx.x, h = blockIdx.y, b = blockIdx.z;
  const short* base = qkv + (ll)b * 2359296;
  const int t = threadIdx.x;
  const int tq = (t >> 4) << 2;
  const int tk = (t & 15) << 2;
  float acc[4][4] = {};
  float ksl = 0.f;
  const int col = t & 31, r0 = t >> 5;
  for (int sub = 0; sub < 4; ++sub) {
    const int m0 = p * 128 + sub * 32;
#pragma unroll
    for (int i = 0; i < 8; ++i) {
      int d = r0 * 8 + i;
      float kvv = b2f(base[(ll)(256 + d * 4 + h) * NPOS + m0 + col]);
      ks[d][col] = kvv > 0.f ? kvv + 1.f : expf(kvv);  // elu+1
      vs[d][col] = b2f(base[(ll)(512 + d * 4 + h) * NPOS + m0 + col]);
    }
    __syncthreads();
#pragma unroll 8
    for (int mm = 0; mm < 32; ++mm) {
      float kk4[4], vv4[4];
#pragma unroll
      for (int i = 0; i < 4; ++i) { kk4[i] = ks[tk + i][mm]; vv4[i] = vs[tq + i][mm]; }
#pragma unroll
      for (int i = 0; i < 4; ++i)
#pragma unroll
        for (int j = 0; j < 4; ++j)
          acc[i][j] = fmaf(vv4[i], kk4[j], acc[i][j]);
    }
    if (t < 64) {
#pragma unroll 8
      for (int mm = 0; mm < 32; ++mm) ksl += ks[t][mm];
    }
    __syncthreads();
  }
  ll o = (((ll)(b * 4 + h)) * 24 + p) * 4096;
#pragma unroll
  for (int i = 0; i < 4; ++i) {
    float4 v; v.x = acc[i][0]; v.y = acc[i][1]; v.z = acc[i][2]; v.w = acc[i][3];
    *(float4*)(kvp + o + (tq + i) * 64 + tk) = v;
  }
  if (t < 64) ksp[((b * 4 + h) * 24 + p) * 64 + t] = ksl;
}

__global__ void kv_reduce_k(const float* __restrict__ kvp, const float* __restrict__ ksp,
                            float* __restrict__ kv, float* __restrict__ ksum)
{
  int bh = blockIdx.x; int t = threadIdx.x;
  for (int e = t; e < 4096; e += 256) {
    float s = 0.f;
    for (int p = 0; p < 24; ++p) s += kvp[((ll)bh * 24 + p) * 4096 + e];
    kv[(ll)bh * 4096 + (ll)(e & 63) * 64 + (e >> 6)] = s;   // [d][qd]
  }
  if (t < 64) {
    float s = 0.f;
    for (int p = 0; p < 24; ++p) s += ksp[((ll)bh * 24 + p) * 64 + t];
    ksum[bh * 64 + t] = s;
  }
}

__global__ __launch_bounds__(256) void attn_out_k(
    const short* __restrict__ qkv, const float* __restrict__ kv,
    const float* __restrict__ ksum, short* __restrict__ obuf)
{
  __shared__ float qt[64][64];     // [d][nl]
  __shared__ float kvT[64][68];    // [d][qd]
  __shared__ float zs[64];
  __shared__ float kss[64];
  const int n0 = blockIdx.x * 64, h = blockIdx.y, b = blockIdx.z;
  const short* qb = qkv + (ll)b * 2359296;
  const int t = threadIdx.x;
  {
    int nl = t & 63; int dg = t >> 6;
#pragma unroll
    for (int i = 0; i < 16; ++i) {
      int d = dg * 16 + i;
      float q = b2f(qb[(ll)(d * 4 + h) * NPOS + n0 + nl]);
      qt[d][nl] = q > 0.f ? q + 1.f : expf(q);  // elu+1
    }
  }
  {
    const float* kvb = kv + (ll)(b * 4 + h) * 4096;
#pragma unroll
    for (int i = 0; i < 16; ++i) {
      int idx = t + i * 256;
      kvT[idx >> 6][idx & 63] = kvb[idx];
    }
  }
  if (t < 64) kss[t] = ksum[(b * 4 + h) * 64 + t];
  __syncthreads();
  if (t < 64) {
    float s = 0.f;
    for (int d = 0; d < 64; ++d) s = fmaf(qt[d][t], kss[d], s);
    zs[t] = 1.f / (s + 1e-6f);
  }
  __syncthreads();
  const int tx = t & 15, ty = t >> 4;
  float acc[4][4] = {};
  for (int d = 0; d < 64; ++d) {
    float a[4], bb[4];
#pragma unroll
    for (int i = 0; i < 4; ++i) a[i] = kvT[d][(ty << 2) + i];
    *(float4*)bb = *(const float4*)&qt[d][tx << 2];
#pragma unroll
    for (int i = 0; i < 4; ++i)
#pragma unroll
      for (int j = 0; j < 4; ++j)
        acc[i][j] = fmaf(a[i], bb[j], acc[i][j]);
  }
  float z4[4];
#pragma unroll
  for (int j = 0; j < 4; ++j) z4[j] = zs[(tx << 2) + j];
#pragma unroll
  for (int i = 0; i < 4; ++i) {
    int qd = (ty << 2) + i;
    short* orow = obuf + (ll)b * 786432 + (ll)(qd * 4 + h) * NPOS + n0;
    uint2 o;
    o.x = pk2(acc[i][0] * z4[0], acc[i][1] * z4[1]);
    o.y = pk2(acc[i][2] * z4[2], acc[i][3] * z4[3]);
    *(uint2*)(orow + (tx << 2)) = o;
  }
}

// ---------------- instnorm (+relu) in place on bf16 rows ----------------
__global__ __launch_bounds__(256) void instnorm_relu_k(short* __restrict__ y)
{
  const ll row = (ll)blockIdx.y * 1572864 + (ll)blockIdx.x * NPOS;
  const int t = threadIdx.x;
  __shared__ float red[4];
  float vals[12];
  float s = 0.f;
#pragma unroll
  for (int i = 0; i < 12; ++i) {
    vals[i] = b2f(y[row + t + i * 256]);
    s += vals[i];
  }
  s = waveSum(s);
  if ((t & 63) == 0) red[t >> 6] = s;
  __syncthreads();
  float mu = (red[0] + red[1] + red[2] + red[3]) * (1.f / NPOS);
  __syncthreads();
  float vs = 0.f;
#pragma unroll
  for (int i = 0; i < 12; ++i) { float d = vals[i] - mu; vs = fmaf(d, d, vs); }
  vs = waveSum(vs);
  if ((t & 63) == 0) red[t >> 6] = vs;
  __syncthreads();
  float var = (red[0] + red[1] + red[2] + red[3]) * (1.f / NPOS);
  float rs = rsqrtf(var + 1e-5f);
#pragma unroll
  for (int i = 0; i < 12; ++i) {
    float v = (vals[i] - mu) * rs;
    y[row + t + i * 256] = f2b(v > 0.f ? v : 0.f);
  }
}

// ---------------- GAT ----------------
__global__ void gat_prep_k(const float* __restrict__ gatW, const float* __restrict__ gata,
                           float* __restrict__ uvec)
{
  int gi = blockIdx.x; int d = threadIdx.x;
  const float* W = gatW + (ll)gi * 65536;
  const float* a = gata + gi * 512;
  float u0 = 0.f, u1 = 0.f;
  for (int o = 0; o < 256; ++o) {
    float w = W[d * 256 + o];
    u0 = fmaf(w, a[o], u0);
    u1 = fmaf(w, a[256 + o], u1);
  }
  uvec[gi * 512 + d] = u0;
  uvec[gi * 512 + 256 + d] = u1;
}

__global__ void gat_edot3_k(const float* __restrict__ x, const float* __restrict__ u,
                            float* __restrict__ e3a, float* __restrict__ e3b)
{
  int n = blockIdx.x * 256 + threadIdx.x; int b = blockIdx.y;
  const float* xb = x + (ll)b * 786432;
  float a0 = 0.f, a1 = 0.f;
  for (int d = 0; d < 256; ++d) {
    float v = xb[(ll)d * NPOS + n];
    a0 = fmaf(v, u[d], a0);
    a1 = fmaf(v, u[256 + d], a1);
  }
  e3a[b * NPOS + n] = a0; e3b[b * NPOS + n] = a1;
}

__global__ void gat_edot2_k(const float* __restrict__ x, const float* __restrict__ u1,
                            float* __restrict__ e2)
{
  int m = blockIdx.x * 256 + threadIdx.x; int b = blockIdx.y;
  const float* xb = x + (ll)b * 6291456;
  float a = 0.f;
  for (int d = 0; d < 256; ++d) a = fmaf(xb[(ll)d * 24576 + m], u1[d], a);
  e2[b * 24576 + m] = a;
}

__global__ void gat_att_k(const float* __restrict__ e3a, const float* __restrict__ e3b,
                          const float* __restrict__ e2, float* __restrict__ att)
{
  int n = blockIdx.x * 256 + threadIdx.x; int b = blockIdx.y;
  float ea = e3a[b * NPOS + n], eb = e3b[b * NPOS + n];
  float e[9];
  e[0] = ea + eb;
  const float* e2b = e2 + (ll)b * 24576 + (ll)n * 8;
#pragma unroll
  for (int l = 0; l < 8; ++l) e[l + 1] = ea + e2b[l];
  float mx = -3.4e38f;
#pragma unroll
  for (int l = 0; l < 9; ++l) {
    e[l] = e[l] >= 0.f ? e[l] : 0.2f * e[l];
    mx = fmaxf(mx, e[l]);
  }
  float s = 0.f;
#pragma unroll
  for (int l = 0; l < 9; ++l) { e[l] = expf(e[l] - mx); s += e[l]; }
  float inv = 1.f / s;
  float* ao = att + ((ll)b * NPOS + n) * 9;
#pragma unroll
  for (int l = 0; l < 9; ++l) ao[l] = e[l] * inv;
}

__global__ void gat_g_k(const float* __restrict__ d3, const float* __restrict__ d2db,
                        const float* __restrict__ att, short* __restrict__ g)
{
  int n = blockIdx.x * 256 + threadIdx.x;
  int d = blockIdx.y; int b = blockIdx.z;
  const float* at = att + ((ll)b * NPOS + n) * 9;
  float s = at[0] * d3[((ll)b * 256 + d) * NPOS + n];
  const float* row = d2db + ((ll)b * 256 + d) * 24576 + (ll)n * 8;
#pragma unroll
  for (int l = 0; l < 8; ++l) s = fmaf(at[l + 1], row[l], s);
  g[((ll)b * 256 + d) * NPOS + n] = f2b(s);
}

// ---------------- final: normalize / softmax / matching ----------------
__global__ void norm_scale_k(const float* __restrict__ v, short* __restrict__ o)
{
  int n = blockIdx.x * 256 + threadIdx.x;
  ll base = (ll)blockIdx.y * 786432 + n;
  float s = 0.f;
  for (int c = 0; c < 256; ++c) { float x = v[base + (ll)c * NPOS]; s = fmaf(x, x, s); }
  float sc = 1.f / fmaxf(sqrtf(s), 1e-12f);
  for (int c = 0; c < 256; ++c) o[base + (ll)c * NPOS] = f2b(v[base + (ll)c * NPOS] * sc);
}

__global__ __launch_bounds__(256) void row_stats_k(const float* __restrict__ S,
                                                   float* __restrict__ rmax, float* __restrict__ rsum)
{
  int n = blockIdx.x; int b = blockIdx.y;
  const float* row = S + (ll)b * 9437184 + (ll)n * NPOS;
  int t = threadIdx.x;
  __shared__ float red[4];
  float mx = -3.4e38f;
  for (int m = t; m < NPOS; m += 256) mx = fmaxf(mx, row[m]);
#pragma unroll
  for (int off = 32; off > 0; off >>= 1) mx = fmaxf(mx, __shfl_down(mx, off));
  if ((t & 63) == 0) red[t >> 6] = mx;
  __syncthreads();
  mx = fmaxf(fmaxf(red[0], red[1]), fmaxf(red[2], red[3]));
  __syncthreads();
  float s = 0.f;
  for (int m = t; m < NPOS; m += 256) s += expf(row[m] - mx);
  s = waveSum(s);
  if ((t & 63) == 0) red[t >> 6] = s;
  __syncthreads();
  if (t == 0) {
    rmax[b * NPOS + n] = mx;
    rsum[b * NPOS + n] = red[0] + red[1] + red[2] + red[3];
  }
}

__global__ void colstat_part_k(const float* __restrict__ S,
                               float* __restrict__ pmax, float* __restrict__ psum)
{
  int m = blockIdx.x * 256 + threadIdx.x;
  int chunk = blockIdx.y; int b = blockIdx.z;
  const float* base = S + (ll)b * 9437184 + m;
  float mx = -3.4e38f, s = 0.f;
  int n0 = chunk * 384;
  for (int n = n0; n < n0 + 384; ++n) {
    float v = base[(ll)n * NPOS];
    if (v > mx) { s = s * expf(mx - v) + 1.f; mx = v; }
    else s += expf(v - mx);
  }
  ll o = ((ll)b * 8 + chunk) * NPOS + m;
  pmax[o] = mx; psum[o] = s;
}

__global__ void colstat_comb_k(const float* __restrict__ pmax, const float* __restrict__ psum,
                               float* __restrict__ cmax, float* __restrict__ csum)
{
  int m = blockIdx.x * 256 + threadIdx.x; int b = blockIdx.y;
  float M = -3.4e38f;
  for (int c = 0; c < 8; ++c) M = fmaxf(M, pmax[((ll)b * 8 + c) * NPOS + m]);
  float s = 0.f;
  for (int c = 0; c < 8; ++c)
    s += psum[((ll)b * 8 + c) * NPOS + m] * expf(pmax[((ll)b * 8 + c) * NPOS + m] - M);
  cmax[b * NPOS + m] = M; csum[b * NPOS + m] = s;
}

__global__ void conf_fix_k(float* __restrict__ S, const float* __restrict__ rmax,
                           const float* __restrict__ rsum, const float* __restrict__ cmax,
                           const float* __restrict__ csum)
{
  ll gi = ((ll)blockIdx.x * 256 + threadIdx.x) * 4;
  int b = (int)(gi / 9437184);
  ll r = gi - (ll)b * 9437184;
  int n = (int)(r / NPOS);
  int m = (int)(r - (ll)n * NPOS);
  float4 v = *(float4*)(S + gi);
  float rm = rmax[b * NPOS + n];
  float irs = 1.f / rsum[b * NPOS + n];
  float* vp = &v.x;
#pragma unroll
  for (int j = 0; j < 4; ++j) {
    float cm = cmax[b * NPOS + m + j];
    float ics = 1.f / csum[b * NPOS + m + j];
    vp[j] = expf(vp[j] - rm) * irs * expf(vp[j] - cm) * ics;
  }
  *(float4*)(S + gi) = v;
}

__global__ __launch_bounds__(256) void argmax_row_k(const float* __restrict__ Cf,
                                                    int* __restrict__ i0, float* __restrict__ m0)
{
  int n = blockIdx.x;
  const float* row = Cf + (ll)n * NPOS;
  int t = threadIdx.x;
  float bv = -1.f; int bi = 0x7fffffff;
  for (int m = t; m < NPOS; m += 256) {
    float v = row[m];
    if (v > bv) { bv = v; bi = m; }
  }
#pragma unroll
  for (int off = 32; off > 0; off >>= 1) {
    float ov = __shfl_down(bv, off);
    int oi = __shfl_down(bi, off);
    if (ov > bv || (ov == bv && oi < bi)) { bv = ov; bi = oi; }
  }
  __shared__ float rv[4]; __shared__ int ri[4];
  if ((t & 63) == 0) { rv[t >> 6] = bv; ri[t >> 6] = bi; }
  __syncthreads();
  if (t == 0) {
    for (int w = 1; w < 4; ++w)
      if (rv[w] > bv || (rv[w] == bv && ri[w] < bi)) { bv = rv[w]; bi = ri[w]; }
    i0[n] = bi; m0[n] = bv;
  }
}

__global__ void argmax_col_k(const float* __restrict__ Cf, int* __restrict__ i1)
{
  int m = blockIdx.x * 256 + threadIdx.x;
  float bv = -1.f; int bi = 0;
  for (int n = 0; n < NPOS; ++n) {
    float v = Cf[(ll)n * NPOS + m];
    if (v > bv) { bv = v; bi = n; }
  }
  i1[m] = bi;
}

__global__ void match0_k(const int* __restrict__ i0, const float* __restrict__ m0,
                         const int* __restrict__ i1, float* __restrict__ out)
{
  int n = blockIdx.x * 256 + threadIdx.x;
  int j = i0[n];
  bool mut = (i1[j] == n);
  float ms0 = mut ? m0[n] : 0.f;
  bool valid = mut && (ms0 > 0.2f);
  out[n] = valid ? (float)j : -1.f;
  out[6144 + n] = ms0;
}

__global__ void match1_k(const int* __restrict__ i0, const int* __restrict__ i1,
                         float* __restrict__ out)
{
  int m = blockIdx.x * 256 + threadIdx.x;
  int j = i1[m];
  bool mut = (i0[j] == m);
  float ms0v = out[6144 + j];
  float ind0v = out[j];
  float ms1 = mut ? ms0v : 0.f;
  bool valid1 = mut && (ind0v >= 0.f);
  out[3072 + m] = valid1 ? (float)j : -1.f;
  out[9216 + m] = ms1;
}

// ------------------------------------------------------------------
extern "C" void kernel_launch(void* const* d_in, const int* in_sizes, int n_in,
                              void* d_out, int out_size, void* d_ws, size_t ws_size,
                              hipStream_t stream)
{
  const float* desc2dq = (const float*)d_in[0];
  const float* desc3db = (const float*)d_in[1];
  const float* desc2db = (const float*)d_in[2];
  const float* projw = (const float*)d_in[3];
  const float* projb = (const float*)d_in[4];
  const float* mergew = (const float*)d_in[5];
  const float* mergeb = (const float*)d_in[6];
  const float* mlp1w = (const float*)d_in[7];
  const float* mlp1b = (const float*)d_in[8];
  const float* mlp2w = (const float*)d_in[9];
  const float* mlp2b = (const float*)d_in[10];
  const float* gatW = (const float*)d_in[11];
  const float* gata = (const float*)d_in[12];
  const float* finw = (const float*)d_in[13];
  const float* finb = (const float*)d_in[14];

  float* ws = (float*)d_ws;
  float* out = (float*)d_out;

  float* dq  = ws + OFF_DQA;
  float* dq2 = ws + OFF_DQB;
  float* d3  = ws + OFF_D3A;
  float* d32 = ws + OFF_D3B;
  short* dqbf  = (short*)(ws + OFF_DQABF);
  short* dq2bf = (short*)(ws + OFF_DQBBF);
  short* d3bf  = (short*)(ws + OFF_D3ABF);
  short* d32bf = (short*)(ws + OFF_D3BBF);
  short* qkvbf = (short*)(ws + OFF_QKV);
  short* obufbf = (short*)(ws + OFF_OBUF);
  short* ybufbf = (short*)(ws + OFF_YBUF);
  short* ybuf2bf = (short*)(ws + OFF_YBUF2);
  short* wbf = (short*)(ws + OFF_WBF);
  short* projw_bf = wbf;
  short* mergew_bf = wbf + 1572864;
  short* mlp1w_bf = wbf + 2097152;
  short* mlp2w_bf = wbf + 4194304;
  short* gatw_bf = wbf + 5242880;
  short* finw_bf = wbf + 5505024;
  float* kvb = ws + OFF_KV;
  float* ksum = ws + OFF_KV + 32768;
  float* kvp = ws + OFF_YBUF2;          // alias: dead outside kv window
  float* ksp = ws + OFF_KSP;
  float* uvec = ws + OFF_UVEC;
  float* e2 = ws + OFF_E2;
  float* e3a = ws + OFF_E3A;
  float* e3b = ws + OFF_E3B;
  float* att = ws + OFF_ATT;
  float* rmax = ws + OFF_RMAX;
  float* rsum = ws + OFF_RSUM;
  float* cmax = ws + OFF_CMAX;
  float* csum = ws + OFF_CSUM;
  float* pmax = ws + OFF_COLP;
  float* psum = ws + OFF_COLP + 49152;
  int* i0 = (int*)(ws + OFF_I0);
  float* m0 = ws + OFF_M0;
  int* i1 = (int*)(ws + OFF_I1);

  auto bgemm = [&](const short* A, const short* B, const float* bias, const float* R,
                   float* C, short* C2, int M, int N, int K, int ta, float alpha,
                   ll aB, ll bB, ll rB, ll cB, ll c2B, int act) {
    bgemm_k<<<dim3(N / 128, M / 128, NB), 256, 0, stream>>>(
        A, B, bias, R, C, C2, M, N, K, ta, alpha, aB, bB, rB, cB, c2B, act);
  };

  // init: fp32 state copies + bf16 conversions + weight conversions
  hipMemcpyAsync(dq, desc2dq, (size_t)1572864 * 4, hipMemcpyDeviceToDevice, stream);
  hipMemcpyAsync(d3, desc3db, (size_t)1572864 * 4, hipMemcpyDeviceToDevice, stream);
  f2b_k<<<768, 256, 0, stream>>>(desc2dq, dqbf, 196608);
  f2b_k<<<768, 256, 0, stream>>>(desc3db, d3bf, 196608);
  f2b_k<<<768, 256, 0, stream>>>(projw, projw_bf, 196608);
  f2b_k<<<256, 256, 0, stream>>>(mergew, mergew_bf, 65536);
  f2b_k<<<1024, 256, 0, stream>>>(mlp1w, mlp1w_bf, 262144);
  f2b_k<<<512, 256, 0, stream>>>(mlp2w, mlp2w_bf, 131072);
  f2b_k<<<128, 256, 0, stream>>>(gatW, gatw_bf, 32768);
  f2b_k<<<32, 256, 0, stream>>>(finw, finw_bf, 8192);
  gat_prep_k<<<4, 256, 0, stream>>>(gatW, gata, uvec);

  auto attn_prop = [&](const float* x, const short* xbf, const short* srcbf,
                       float* xo, short* xobf, int ai) {
    bgemm(projw_bf + (ll)ai * 3 * 65536, xbf, projb + (ll)ai * 768, nullptr,
          nullptr, qkvbf, 256, NPOS, 256, 0, 1.f, 0, 786432, 0, 0, 2359296, 0);
    bgemm(projw_bf + (ll)ai * 3 * 65536 + 65536, srcbf, projb + (ll)ai * 768 + 256, nullptr,
          nullptr, qkvbf + 786432, 512, NPOS, 256, 0, 1.f, 0, 786432, 0, 0, 2359296, 0);
    kv_partial_k<<<dim3(24, 4, NB), 256, 0, stream>>>(qkvbf, kvp, ksp);
    kv_reduce_k<<<8, 256, 0, stream>>>(kvp, ksp, kvb, ksum);
    attn_out_k<<<dim3(48, 4, NB), 256, 0, stream>>>(qkvbf, kvb, ksum, obufbf);
    bgemm(mergew_bf + (ll)ai * 65536, obufbf, mergeb + (ll)ai * 256, nullptr,
          nullptr, ybufbf + 786432, 256, NPOS, 256, 0, 1.f, 0, 786432, 0, 0, 1572864, 0);
    xcopy_k<<<768, 256, 0, stream>>>(x, ybufbf);
    bgemm(mlp1w_bf + (ll)ai * 262144, ybufbf, mlp1b + (ll)ai * 512, nullptr,
          nullptr, ybuf2bf, 512, NPOS, 512, 0, 1.f, 0, 1572864, 0, 0, 1572864, 0);
    instnorm_relu_k<<<dim3(512, NB), 256, 0, stream>>>(ybuf2bf);
    bgemm(mlp2w_bf + (ll)ai * 131072, ybuf2bf, mlp2b + (ll)ai * 256, x,
          xo, xobf, 256, NPOS, 512, 0, 1.f, 0, 1572864, 786432, 786432, 786432, 0);
  };

  auto gat_layer = [&](const float* din, float* dout, short* doutbf, int gi) {
    const float* uv = uvec + gi * 512;
    gat_edot3_k<<<dim3(12, NB), 256, 0, stream>>>(din, uv, e3a, e3b);
    gat_edot2_k<<<dim3(96, NB), 256, 0, stream>>>(desc2db, uv + 256, e2);
    gat_att_k<<<dim3(12, NB), 256, 0, stream>>>(e3a, e3b, e2, att);
    gat_g_k<<<dim3(12, 256, NB), 256, 0, stream>>>(din, desc2db, att, obufbf);
    // h = W^T @ g (ta=1), elu, dual write
    bgemm(gatw_bf + (ll)gi * 65536, obufbf, nullptr, nullptr,
          dout, doutbf, 256, NPOS, 256, 1, 1.f, 0, 786432, 0, 786432, 786432, 1);
  };

  int ai = 0, gi = 0;
  for (int r = 0; r < 4; ++r) {
    gat_layer(d3, d32, d32bf, gi);
    { float* t_ = d3; d3 = d32; d32 = t_; }
    { short* t_ = d3bf; d3bf = d32bf; d32bf = t_; }
    gi++;
    // self
    attn_prop(dq, dqbf, dqbf, dq2, dq2bf, ai);
    attn_prop(d3, d3bf, d3bf, d32, d32bf, ai);
    { float* t_ = dq; dq = dq2; dq2 = t_; }
    { short* t_ = dqbf; dqbf = dq2bf; dq2bf = t_; }
    { float* t_ = d3; d3 = d32; d32 = t_; }
    { short* t_ = d3bf; d3bf = d32bf; d32bf = t_; }
    ai++;
    // cross (d3's update uses OLD dq)
    attn_prop(dq, dqbf, d3bf, dq2, dq2bf, ai);
    attn_prop(d3, d3bf, dqbf, d32, d32bf, ai);
    { float* t_ = dq; dq = dq2; dq2 = t_; }
    { short* t_ = dqbf; dqbf = dq2bf; dq2bf = t_; }
    { float* t_ = d3; d3 = d32; d32 = t_; }
    { short* t_ = d3bf; d3bf = d32bf; d32bf = t_; }
    ai++;
  }

  // final projection + L2 normalize (aliases: mq->YBUF2, md->QKV, bf in YBUF)
  float* mq = ws + OFF_YBUF2;
  float* md = ws + OFF_QKV;
  short* mqbf = (short*)(ws + OFF_YBUF);
  short* mdbf = (short*)(ws + OFF_YBUF) + 786432;
  bgemm(finw_bf, dqbf, finb, nullptr, mq, nullptr, 256, NPOS, 256, 0, 1.f,
        0, 786432, 0, 786432, 0, 0);
  bgemm(finw_bf, d3bf, finb, nullptr, md, nullptr, 256, NPOS, 256, 0, 1.f,
        0, 786432, 0, 786432, 0, 0);
  norm_scale_k<<<dim3(12, NB), 256, 0, stream>>>(mq, mqbf);
  norm_scale_k<<<dim3(12, NB), 256, 0, stream>>>(md, mdbf);

  // scores = 10 * mq^T md -> conf region of d_out
  float* conf = out + 12288;
  bgemm(mqbf, mdbf, nullptr, nullptr, conf, nullptr, NPOS, NPOS, 256, 1, 10.f,
        786432, 786432, 0, 9437184, 0, 0);

  row_stats_k<<<dim3(NPOS, NB), 256, 0, stream>>>(conf, rmax, rsum);
  colstat_part_k<<<dim3(12, 8, NB), 256, 0, stream>>>(conf, pmax, psum);
  colstat_comb_k<<<dim3(12, NB), 256, 0, stream>>>(pmax, psum, cmax, csum);
  conf_fix_k<<<18432, 256, 0, stream>>>(conf, rmax, rsum, cmax, csum);

  argmax_row_k<<<NPOS, 256, 0, stream>>>(conf, i0, m0);
  argmax_col_k<<<12, 256, 0, stream>>>(conf, i1);
  match0_k<<<12, 256, 0, stream>>>(i0, m0, i1, out);
  match1_k<<<12, 256, 0, stream>>>(i0, i1, out);
}

// Round 3
// 2082.913 us; speedup vs baseline: 2.1113x; 1.8396x over previous
//
#include <hip/hip_runtime.h>
#include <hip/hip_bf16.h>
#include <math.h>

typedef long long ll;
typedef __attribute__((ext_vector_type(8))) short s8v;
typedef __attribute__((ext_vector_type(4))) float f4v;

#define NPOS 3072
// state z layout: [0]=dq_b0 [1]=dq_b1 [2]=d3_b0 [3]=d3_b1

// ---------------- workspace offsets (in floats) ----------------
#define OFF_STF   0LL          /* fp32 state [4][256][3072] */
#define OFF_STB   3145728LL    /* bf16 state [4][256][3072] shorts */
#define OFF_QKV   4718592LL    /* bf16 qkv [4][768][3072] shorts */
#define OFF_MSG   9437184LL    /* bf16 msg [4][256][3072] shorts; fin-proj bf16 alias */
#define OFF_HID   11010048LL   /* bf16 hid [4][512][3072] shorts; obuf=lower half, kvp=upper */
#define OFF_WBF   14155776LL   /* bf16 weights (5,570,560 shorts) */
#define OFF_KV    16941056LL
#define OFF_KSUM  17006592LL
#define OFF_KSP   17007616LL
#define OFF_UVEC  17032192LL
#define OFF_E3PA  17034240LL
#define OFF_E3PB  17083392LL
#define OFF_E2P   17132544LL
#define OFF_ATT   17230848LL
#define OFF_SVEC  17286144LL
#define OFF_PMAX  17298432LL
#define OFF_PSUM  17593344LL
#define OFF_CMAX  17888256LL
#define OFF_CSUM  17894400LL
#define OFF_CAPV  17900544LL
#define OFF_CAPI  17974272LL
#define OFF_I0    18048000LL
#define OFF_M0    18051072LL
#define OFF_I1    18054144LL

__device__ __forceinline__ float b2f(short s) {
  union { unsigned u; float f; } c;
  c.u = ((unsigned)(unsigned short)s) << 16;
  return c.f;
}
__device__ __forceinline__ short f2b(float f) {
  __hip_bfloat16 h = __float2bfloat16(f);
  union { __hip_bfloat16 h; short s; } c; c.h = h; return c.s;
}
__device__ __forceinline__ unsigned pk2(float a, float b) {
  return (unsigned)(unsigned short)f2b(a) | ((unsigned)(unsigned short)f2b(b) << 16);
}
__device__ __forceinline__ float waveSum(float v) {
#pragma unroll
  for (int off = 32; off > 0; off >>= 1) v += __shfl_down(v, off);
  return v;
}

// ------------------------------------------------------------------
// bf16 MFMA GEMM with optional split-B, z-offset B batching, row/col
// scale epilogue, fp32/bf16 outputs, fp32 residual, elu.
// A: ta=0 [M,K], ta=1 [K,M] row-major bf16. B rows k<KS from B, k>=KS
// from B2 (row k-KS). zz = (z+zb)&3 selects B batch. M%128, N%128, K%32.
// ------------------------------------------------------------------
__global__ __launch_bounds__(256) void bgemm_k(
    const short* __restrict__ A, const short* __restrict__ B,
    const short* __restrict__ B2, int KS,
    const float* __restrict__ bias, const float* __restrict__ R,
    float* __restrict__ C, short* __restrict__ C2,
    const float* __restrict__ rs, const float* __restrict__ cs,
    int M, int N, int K, int ta, float alpha,
    ll aB, ll bB, ll b2B, ll rB, ll cB, ll c2B,
    int zb, int act)
{
  __shared__ __align__(16) short As[128 * 40];
  __shared__ __align__(16) short Bs[128 * 40];
  const int z = blockIdx.z;
  const int zz = (z + zb) & 3;
  const short* Ab = A + (ll)z * aB;
  const short* Bb = B + (ll)zz * bB;
  const short* B2b = B2 ? B2 + (ll)zz * b2B : (const short*)0;
  const int n0 = blockIdx.x * 128, m0 = blockIdx.y * 128;
  const int t = threadIdx.x;
  const int lane = t & 63, w = t >> 6;
  const int wm = (w & 1) * 64, wn = (w >> 1) * 64;
  const int fr = lane & 15;
  const int k8 = (lane >> 4) * 8;
  const int lda = ta ? M : K;

  f4v acc[4][4];
#pragma unroll
  for (int i = 0; i < 4; ++i)
#pragma unroll
    for (int j = 0; j < 4; ++j) acc[i][j] = (f4v)0.f;

  for (int k0 = 0; k0 < K; k0 += 32) {
    if (ta == 0) {
#pragma unroll
      for (int i = 0; i < 2; ++i) {
        int c = t + i * 256;
        int m = c >> 2, kq = (c & 3) * 8;
        uint4 v = *(const uint4*)(Ab + (ll)(m0 + m) * lda + k0 + kq);
        *(uint4*)(As + m * 40 + kq) = v;
      }
    } else {
#pragma unroll
      for (int i = 0; i < 2; ++i) {
        int c = t + i * 256;
        int kp = c & 15, mq = (c >> 4) * 4;
        const short* p0 = Ab + (ll)(k0 + kp * 2) * lda + m0 + mq;
        uint2 r0 = *(const uint2*)p0;
        uint2 r1 = *(const uint2*)(p0 + lda);
        unsigned s0[4] = { r0.x & 0xffffu, r0.x >> 16, r0.y & 0xffffu, r0.y >> 16 };
        unsigned s1[4] = { r1.x & 0xffffu, r1.x >> 16, r1.y & 0xffffu, r1.y >> 16 };
#pragma unroll
        for (int j = 0; j < 4; ++j)
          *(unsigned*)(As + (mq + j) * 40 + kp * 2) = s0[j] | (s1[j] << 16);
      }
    }
    {
      const short* Bsrc = Bb;
      ll krow = k0;
      if (B2b && k0 >= KS) { Bsrc = B2b; krow = k0 - KS; }
#pragma unroll
      for (int i = 0; i < 2; ++i) {
        int c = t + i * 256;
        int kp = c & 15, nq = (c >> 4) * 4;
        const short* p0 = Bsrc + (krow + kp * 2) * (ll)N + n0 + nq;
        uint2 r0 = *(const uint2*)p0;
        uint2 r1 = *(const uint2*)(p0 + N);
        unsigned s0[4] = { r0.x & 0xffffu, r0.x >> 16, r0.y & 0xffffu, r0.y >> 16 };
        unsigned s1[4] = { r1.x & 0xffffu, r1.x >> 16, r1.y & 0xffffu, r1.y >> 16 };
#pragma unroll
        for (int j = 0; j < 4; ++j)
          *(unsigned*)(Bs + (nq + j) * 40 + kp * 2) = s0[j] | (s1[j] << 16);
      }
    }
    __syncthreads();
    s8v af[4], bfr[4];
#pragma unroll
    for (int im = 0; im < 4; ++im)
      af[im] = *(const s8v*)(As + (wm + im * 16 + fr) * 40 + k8);
#pragma unroll
    for (int in = 0; in < 4; ++in)
      bfr[in] = *(const s8v*)(Bs + (wn + in * 16 + fr) * 40 + k8);
#pragma unroll
    for (int im = 0; im < 4; ++im)
#pragma unroll
      for (int in = 0; in < 4; ++in)
        acc[im][in] = __builtin_amdgcn_mfma_f32_16x16x32_bf16(
            af[im], bfr[in], acc[im][in], 0, 0, 0);
    __syncthreads();
  }

  const int q4 = (lane >> 4) * 4;
#pragma unroll
  for (int im = 0; im < 4; ++im) {
#pragma unroll
    for (int r = 0; r < 4; ++r) {
      int m = m0 + wm + im * 16 + q4 + r;
      float bv = bias ? bias[m] : 0.f;
      float rsv = rs ? rs[(ll)z * M + m] : 1.f;
#pragma unroll
      for (int in = 0; in < 4; ++in) {
        int n = n0 + wn + in * 16 + fr;
        float v = acc[im][in][r] * alpha;
        if (rs) v *= rsv * cs[(ll)zz * N + n];
        v += bv;
        ll off = (ll)m * N + n;
        if (R) v += R[(ll)z * rB + off];
        if (act) v = v > 0.f ? v : (expf(v) - 1.f);
        if (C) C[(ll)z * cB + off] = v;
        if (C2) C2[(ll)z * c2B + off] = f2b(v);
      }
    }
  }
}

// ---------------- fp32 -> bf16 ----------------
__global__ void f2b_k(const float* __restrict__ src, short* __restrict__ dst, int n8)
{
  int gi = blockIdx.x * 256 + threadIdx.x;
  if (gi >= n8) return;
  ll e = (ll)gi * 8;
  float4 a = *(const float4*)(src + e);
  float4 b = *(const float4*)(src + e + 4);
  uint4 o;
  o.x = pk2(a.x, a.y); o.y = pk2(a.z, a.w);
  o.z = pk2(b.x, b.y); o.w = pk2(b.z, b.w);
  *(uint4*)(dst + e) = o;
}

// ---------------- linear attention (batch 4) ----------------
__global__ __launch_bounds__(256) void kv_partial_k(
    const short* __restrict__ qkv, float* __restrict__ kvp, float* __restrict__ ksp)
{
  __shared__ float ks[64][33];
  __shared__ float vs[64][33];
  const int p = blockIdx.x, h = blockIdx.y, z = blockIdx.z;
  const short* base = qkv + (ll)z * 2359296;
  const int t = threadIdx.x;
  const int tq = (t >> 4) << 2;
  const int tk = (t & 15) << 2;
  float acc[4][4] = {};
  float ksl = 0.f;
  const int col = t & 31, r0 = t >> 5;
  for (int sub = 0; sub < 4; ++sub) {
    const int m0 = p * 128 + sub * 32;
#pragma unroll
    for (int i = 0; i < 8; ++i) {
      int d = r0 * 8 + i;
      float kvv = b2f(base[(ll)(256 + d * 4 + h) * NPOS + m0 + col]);
      ks[d][col] = kvv > 0.f ? kvv + 1.f : expf(kvv);
      vs[d][col] = b2f(base[(ll)(512 + d * 4 + h) * NPOS + m0 + col]);
    }
    __syncthreads();
#pragma unroll 8
    for (int mm = 0; mm < 32; ++mm) {
      float kk4[4], vv4[4];
#pragma unroll
      for (int i = 0; i < 4; ++i) { kk4[i] = ks[tk + i][mm]; vv4[i] = vs[tq + i][mm]; }
#pragma unroll
      for (int i = 0; i < 4; ++i)
#pragma unroll
        for (int j = 0; j < 4; ++j)
          acc[i][j] = fmaf(vv4[i], kk4[j], acc[i][j]);
    }
    if (t < 64) {
#pragma unroll 8
      for (int mm = 0; mm < 32; ++mm) ksl += ks[t][mm];
    }
    __syncthreads();
  }
  ll o = (((ll)(z * 4 + h)) * 24 + p) * 4096;
#pragma unroll
  for (int i = 0; i < 4; ++i) {
    float4 v; v.x = acc[i][0]; v.y = acc[i][1]; v.z = acc[i][2]; v.w = acc[i][3];
    *(float4*)(kvp + o + (tq + i) * 64 + tk) = v;
  }
  if (t < 64) ksp[((z * 4 + h) * 24 + p) * 64 + t] = ksl;
}

__global__ void kv_reduce_k(const float* __restrict__ kvp, const float* __restrict__ ksp,
                            float* __restrict__ kv, float* __restrict__ ksum)
{
  int bh = blockIdx.x; int t = threadIdx.x;
  for (int e = t; e < 4096; e += 256) {
    float s = 0.f;
    for (int p = 0; p < 24; ++p) s += kvp[((ll)bh * 24 + p) * 4096 + e];
    kv[(ll)bh * 4096 + (ll)(e & 63) * 64 + (e >> 6)] = s;   // [d][qd]
  }
  if (t < 64) {
    float s = 0.f;
    for (int p = 0; p < 24; ++p) s += ksp[((ll)bh * 24 + p) * 64 + t];
    ksum[bh * 64 + t] = s;
  }
}

__global__ __launch_bounds__(256) void attn_out_k(
    const short* __restrict__ qkv, const float* __restrict__ kv,
    const float* __restrict__ ksum, short* __restrict__ obuf)
{
  __shared__ float qt[64][64];
  __shared__ float kvT[64][68];
  __shared__ float zsh[64];
  __shared__ float kss[64];
  const int n0 = blockIdx.x * 64, h = blockIdx.y, z = blockIdx.z;
  const short* qb = qkv + (ll)z * 2359296;
  const int t = threadIdx.x;
  {
    int nl = t & 63; int dg = t >> 6;
#pragma unroll
    for (int i = 0; i < 16; ++i) {
      int d = dg * 16 + i;
      float q = b2f(qb[(ll)(d * 4 + h) * NPOS + n0 + nl]);
      qt[d][nl] = q > 0.f ? q + 1.f : expf(q);
    }
  }
  {
    const float* kvb = kv + (ll)(z * 4 + h) * 4096;
#pragma unroll
    for (int i = 0; i < 16; ++i) {
      int idx = t + i * 256;
      kvT[idx >> 6][idx & 63] = kvb[idx];
    }
  }
  if (t < 64) kss[t] = ksum[(z * 4 + h) * 64 + t];
  __syncthreads();
  if (t < 64) {
    float s = 0.f;
    for (int d = 0; d < 64; ++d) s = fmaf(qt[d][t], kss[d], s);
    zsh[t] = 1.f / (s + 1e-6f);
  }
  __syncthreads();
  const int tx = t & 15, ty = t >> 4;
  float acc[4][4] = {};
  for (int d = 0; d < 64; ++d) {
    float a[4], bb[4];
#pragma unroll
    for (int i = 0; i < 4; ++i) a[i] = kvT[d][(ty << 2) + i];
    *(float4*)bb = *(const float4*)&qt[d][tx << 2];
#pragma unroll
    for (int i = 0; i < 4; ++i)
#pragma unroll
      for (int j = 0; j < 4; ++j)
        acc[i][j] = fmaf(a[i], bb[j], acc[i][j]);
  }
  float z4[4];
#pragma unroll
  for (int j = 0; j < 4; ++j) z4[j] = zsh[(tx << 2) + j];
#pragma unroll
  for (int i = 0; i < 4; ++i) {
    int qd = (ty << 2) + i;
    short* orow = obuf + (ll)z * 786432 + (ll)(qd * 4 + h) * NPOS + n0;
    uint2 o;
    o.x = pk2(acc[i][0] * z4[0], acc[i][1] * z4[1]);
    o.y = pk2(acc[i][2] * z4[2], acc[i][3] * z4[3]);
    *(uint2*)(orow + (tx << 2)) = o;
  }
}

// ---------------- instnorm+relu in place, bf16 rows, batch 4 ----------------
__global__ __launch_bounds__(256) void instnorm_relu_k(short* __restrict__ y)
{
  const ll row = (ll)blockIdx.y * 1572864 + (ll)blockIdx.x * NPOS;
  const int t = threadIdx.x;
  __shared__ float red[4];
  float vals[12];
  float s = 0.f;
#pragma unroll
  for (int i = 0; i < 12; ++i) {
    vals[i] = b2f(y[row + t + i * 256]);
    s += vals[i];
  }
  s = waveSum(s);
  if ((t & 63) == 0) red[t >> 6] = s;
  __syncthreads();
  float mu = (red[0] + red[1] + red[2] + red[3]) * (1.f / NPOS);
  __syncthreads();
  float vsum = 0.f;
#pragma unroll
  for (int i = 0; i < 12; ++i) { float d = vals[i] - mu; vsum = fmaf(d, d, vsum); }
  vsum = waveSum(vsum);
  if ((t & 63) == 0) red[t >> 6] = vsum;
  __syncthreads();
  float var = (red[0] + red[1] + red[2] + red[3]) * (1.f / NPOS);
  float rsq = rsqrtf(var + 1e-5f);
#pragma unroll
  for (int i = 0; i < 12; ++i) {
    float v = (vals[i] - mu) * rsq;
    y[row + t + i * 256] = f2b(v > 0.f ? v : 0.f);
  }
}

// ---------------- GAT ----------------
__global__ void gat_prep_k(const float* __restrict__ gatW, const float* __restrict__ gata,
                           float* __restrict__ uvec)
{
  int gi = blockIdx.x; int d = threadIdx.x;
  const float* W = gatW + (ll)gi * 65536;
  const float* a = gata + gi * 512;
  float u0 = 0.f, u1 = 0.f;
  for (int o = 0; o < 256; ++o) {
    float w = W[d * 256 + o];
    u0 = fmaf(w, a[o], u0);
    u1 = fmaf(w, a[256 + o], u1);
  }
  uvec[gi * 512 + d] = u0;
  uvec[gi * 512 + 256 + d] = u1;
}

// e3 partials: channel chunk of 32. grid (12, 8, 2)
__global__ void gat_edot3_k(const short* __restrict__ stb, const float* __restrict__ u,
                            float* __restrict__ e3pa, float* __restrict__ e3pb)
{
  int n = blockIdx.x * 256 + threadIdx.x;
  int cy = blockIdx.y, b = blockIdx.z;
  const short* xb = stb + (ll)(2 + b) * 786432;
  int c0 = cy * 32;
  float a0 = 0.f, a1 = 0.f;
#pragma unroll
  for (int i = 0; i < 32; ++i) {
    float v = b2f(xb[(ll)(c0 + i) * NPOS + n]);
    a0 = fmaf(v, u[c0 + i], a0);
    a1 = fmaf(v, u[256 + c0 + i], a1);
  }
  e3pa[(cy * 2 + b) * NPOS + n] = a0;
  e3pb[(cy * 2 + b) * NPOS + n] = a1;
}

// e2 partials: channel chunk of 128. grid (96, 2, 2)
__global__ void gat_edot2_k(const float* __restrict__ d2db, const float* __restrict__ u1,
                            float* __restrict__ e2p)
{
  int m = blockIdx.x * 256 + threadIdx.x;
  int cz = blockIdx.y, b = blockIdx.z;
  const float* xb = d2db + (ll)b * 6291456;
  int c0 = cz * 128;
  float a = 0.f;
  for (int c = c0; c < c0 + 128; ++c) a = fmaf(xb[(ll)c * 24576 + m], u1[c], a);
  e2p[((ll)cz * 2 + b) * 24576 + m] = a;
}

__global__ void gat_att_k(const float* __restrict__ e3pa, const float* __restrict__ e3pb,
                          const float* __restrict__ e2p, float* __restrict__ att)
{
  int n = blockIdx.x * 256 + threadIdx.x; int b = blockIdx.y;
  float ea = 0.f, eb = 0.f;
#pragma unroll
  for (int p = 0; p < 8; ++p) {
    ea += e3pa[(p * 2 + b) * NPOS + n];
    eb += e3pb[(p * 2 + b) * NPOS + n];
  }
  float e[9];
  e[0] = ea + eb;
#pragma unroll
  for (int l = 0; l < 8; ++l)
    e[l + 1] = ea + e2p[(ll)b * 24576 + (ll)n * 8 + l] + e2p[(ll)(2 + b) * 24576 + (ll)n * 8 + l];
  float mx = -3.4e38f;
#pragma unroll
  for (int l = 0; l < 9; ++l) {
    e[l] = e[l] >= 0.f ? e[l] : 0.2f * e[l];
    mx = fmaxf(mx, e[l]);
  }
  float s = 0.f;
#pragma unroll
  for (int l = 0; l < 9; ++l) { e[l] = expf(e[l] - mx); s += e[l]; }
  float inv = 1.f / s;
  float* ao = att + ((ll)b * NPOS + n) * 9;
#pragma unroll
  for (int l = 0; l < 9; ++l) ao[l] = e[l] * inv;
}

// g = att-weighted combine -> obuf slots 0..1. grid (12, 256, 2)
__global__ void gat_g_k(const short* __restrict__ stb, const float* __restrict__ d2db,
                        const float* __restrict__ att, short* __restrict__ g)
{
  int n = blockIdx.x * 256 + threadIdx.x;
  int d = blockIdx.y; int b = blockIdx.z;
  const float* at = att + ((ll)b * NPOS + n) * 9;
  float s = at[0] * b2f(stb[(ll)(2 + b) * 786432 + (ll)d * NPOS + n]);
  const float* row = d2db + ((ll)b * 256 + d) * 24576 + (ll)n * 8;
#pragma unroll
  for (int l = 0; l < 8; ++l) s = fmaf(at[l + 1], row[l], s);
  g[((ll)b * 256 + d) * NPOS + n] = f2b(s);
}

// ---------------- final epilogue ----------------
// column inverse L2 norms of fin-proj bf16 [4][256][3072] -> svec[4][3072]
__global__ void normcalc_k(const short* __restrict__ f, float* __restrict__ svec)
{
  int z = blockIdx.y; int t = threadIdx.x;
  int n = blockIdx.x * 64 + (t & 63); int cg = t >> 6;
  const short* base = f + (ll)z * 786432 + n;
  float s = 0.f;
#pragma unroll 16
  for (int i = 0; i < 64; ++i) {
    float v = b2f(base[(ll)(cg * 64 + i) * NPOS]);
    s = fmaf(v, v, s);
  }
  __shared__ float red[4][64];
  red[cg][t & 63] = s;
  __syncthreads();
  if (t < 64) {
    float tot = red[0][t] + red[1][t] + red[2][t] + red[3][t];
    svec[z * NPOS + blockIdx.x * 64 + t] = 1.f / fmaxf(sqrtf(tot), 1e-12f);
  }
}

// col softmax partials over raw scores. grid (12, 48, 2)
__global__ void colstat_part_k(const float* __restrict__ S,
                               float* __restrict__ pmax, float* __restrict__ psum)
{
  int m = blockIdx.x * 256 + threadIdx.x;
  int chunk = blockIdx.y; int b = blockIdx.z;
  const float* base = S + (ll)b * 9437184 + m;
  float mx = -3.4e38f, s = 0.f;
  int n0 = chunk * 64;
  for (int n = n0; n < n0 + 64; ++n) {
    float v = base[(ll)n * NPOS];
    if (v > mx) { s = s * expf(mx - v) + 1.f; mx = v; }
    else s += expf(v - mx);
  }
  ll o = ((ll)b * 48 + chunk) * NPOS + m;
  pmax[o] = mx; psum[o] = s;
}

__global__ void colstat_comb_k(const float* __restrict__ pmax, const float* __restrict__ psum,
                               float* __restrict__ cmax, float* __restrict__ csum)
{
  int m = blockIdx.x * 256 + threadIdx.x; int b = blockIdx.y;
  float M = -3.4e38f;
  for (int c = 0; c < 48; ++c) M = fmaxf(M, pmax[((ll)b * 48 + c) * NPOS + m]);
  float s = 0.f;
  for (int c = 0; c < 48; ++c)
    s += psum[((ll)b * 48 + c) * NPOS + m] * expf(pmax[((ll)b * 48 + c) * NPOS + m] - M);
  cmax[b * NPOS + m] = M; csum[b * NPOS + m] = s;
}

// single pass: row stats + dual-softmax fix + row argmax (b==0). grid (3072, 2)
__global__ __launch_bounds__(256) void rowfix_k(
    float* __restrict__ S, const float* __restrict__ cmax, const float* __restrict__ csum,
    int* __restrict__ i0, float* __restrict__ m0)
{
  int n = blockIdx.x, b = blockIdx.y, t = threadIdx.x;
  float* row = S + (ll)b * 9437184 + (ll)n * NPOS;
  __shared__ float red[4];
  float v[12];
  float mx = -3.4e38f;
#pragma unroll
  for (int i = 0; i < 12; ++i) { v[i] = row[t + i * 256]; mx = fmaxf(mx, v[i]); }
#pragma unroll
  for (int off = 32; off > 0; off >>= 1) mx = fmaxf(mx, __shfl_down(mx, off));
  if ((t & 63) == 0) red[t >> 6] = mx;
  __syncthreads();
  float rm = fmaxf(fmaxf(red[0], red[1]), fmaxf(red[2], red[3]));
  __syncthreads();
  float s = 0.f;
#pragma unroll
  for (int i = 0; i < 12; ++i) s += expf(v[i] - rm);
  s = waveSum(s);
  if ((t & 63) == 0) red[t >> 6] = s;
  __syncthreads();
  float irs = 1.f / (red[0] + red[1] + red[2] + red[3]);
  float bv = -1.f; int bi = 0;
#pragma unroll
  for (int i = 0; i < 12; ++i) {
    int m = t + i * 256;
    float f = expf(2.f * v[i] - rm - cmax[b * NPOS + m]) * irs / csum[b * NPOS + m];
    row[m] = f;
    if (f > bv) { bv = f; bi = m; }
  }
  if (b == 0) {
#pragma unroll
    for (int off = 32; off > 0; off >>= 1) {
      float ov = __shfl_down(bv, off);
      int oi = __shfl_down(bi, off);
      if (ov > bv || (ov == bv && oi < bi)) { bv = ov; bi = oi; }
    }
    __shared__ float rv[4]; __shared__ int ri[4];
    if ((t & 63) == 0) { rv[t >> 6] = bv; ri[t >> 6] = bi; }
    __syncthreads();
    if (t == 0) {
      for (int w = 1; w < 4; ++w)
        if (rv[w] > bv || (rv[w] == bv && ri[w] < bi)) { bv = rv[w]; bi = ri[w]; }
      i0[n] = bi; m0[n] = bv;
    }
  }
}

// col argmax partials on fixed conf b=0. grid (12, 24)
__global__ void colamax_part_k(const float* __restrict__ Cf,
                               float* __restrict__ capv, int* __restrict__ capi)
{
  int m = blockIdx.x * 256 + threadIdx.x;
  int n0 = blockIdx.y * 128;
  float bv = -1.f; int bi = 0;
  for (int n = n0; n < n0 + 128; ++n) {
    float f = Cf[(ll)n * NPOS + m];
    if (f > bv) { bv = f; bi = n; }
  }
  capv[blockIdx.y * NPOS + m] = bv;
  capi[blockIdx.y * NPOS + m] = bi;
}

__global__ void colamax_comb_k(const float* __restrict__ capv, const int* __restrict__ capi,
                               int* __restrict__ i1)
{
  int m = blockIdx.x * 256 + threadIdx.x;
  float bv = -1.f; int bi = 0;
  for (int c = 0; c < 24; ++c) {
    float v = capv[c * NPOS + m];
    if (v > bv) { bv = v; bi = capi[c * NPOS + m]; }
  }
  i1[m] = bi;
}

__global__ void match0_k(const int* __restrict__ i0, const float* __restrict__ m0,
                         const int* __restrict__ i1, float* __restrict__ out)
{
  int n = blockIdx.x * 256 + threadIdx.x;
  int j = i0[n];
  bool mut = (i1[j] == n);
  float ms0 = mut ? m0[n] : 0.f;
  bool valid = mut && (ms0 > 0.2f);
  out[n] = valid ? (float)j : -1.f;
  out[6144 + n] = ms0;
}

__global__ void match1_k(const int* __restrict__ i0, const int* __restrict__ i1,
                         float* __restrict__ out)
{
  int m = blockIdx.x * 256 + threadIdx.x;
  int j = i1[m];
  bool mut = (i0[j] == m);
  float ms0v = out[6144 + j];
  float ind0v = out[j];
  float ms1 = mut ? ms0v : 0.f;
  bool valid1 = mut && (ind0v >= 0.f);
  out[3072 + m] = valid1 ? (float)j : -1.f;
  out[9216 + m] = ms1;
}

// ------------------------------------------------------------------
extern "C" void kernel_launch(void* const* d_in, const int* in_sizes, int n_in,
                              void* d_out, int out_size, void* d_ws, size_t ws_size,
                              hipStream_t stream)
{
  const float* desc2dq = (const float*)d_in[0];
  const float* desc3db = (const float*)d_in[1];
  const float* desc2db = (const float*)d_in[2];
  const float* projw = (const float*)d_in[3];
  const float* projb = (const float*)d_in[4];
  const float* mergew = (const float*)d_in[5];
  const float* mergeb = (const float*)d_in[6];
  const float* mlp1w = (const float*)d_in[7];
  const float* mlp1b = (const float*)d_in[8];
  const float* mlp2w = (const float*)d_in[9];
  const float* mlp2b = (const float*)d_in[10];
  const float* gatW = (const float*)d_in[11];
  const float* gata = (const float*)d_in[12];
  const float* finw = (const float*)d_in[13];
  const float* finb = (const float*)d_in[14];

  float* ws = (float*)d_ws;
  float* out = (float*)d_out;

  float* stf = ws + OFF_STF;
  short* stb = (short*)(ws + OFF_STB);
  short* qkv = (short*)(ws + OFF_QKV);
  short* msg = (short*)(ws + OFF_MSG);
  short* hid = (short*)(ws + OFF_HID);
  short* obuf = hid;                       // alias: lower half of hid
  float* kvp = ws + OFF_HID + 1572864;     // alias: upper half of hid
  short* wbf = (short*)(ws + OFF_WBF);
  short* projw_bf = wbf;
  short* mergew_bf = wbf + 1572864;
  short* mlp1w_bf = wbf + 2097152;
  short* mlp2w_bf = wbf + 4194304;
  short* gatw_bf = wbf + 5242880;
  short* finw_bf = wbf + 5505024;
  float* kvb = ws + OFF_KV;
  float* ksum = ws + OFF_KSUM;
  float* ksp = ws + OFF_KSP;
  float* uvec = ws + OFF_UVEC;
  float* e3pa = ws + OFF_E3PA;
  float* e3pb = ws + OFF_E3PB;
  float* e2p = ws + OFF_E2P;
  float* att = ws + OFF_ATT;
  float* svec = ws + OFF_SVEC;
  float* pmax = ws + OFF_PMAX;
  float* psum = ws + OFF_PSUM;
  float* cmax = ws + OFF_CMAX;
  float* csum = ws + OFF_CSUM;
  float* capv = ws + OFF_CAPV;
  int* capi = (int*)(ws + OFF_CAPI);
  int* i0 = (int*)(ws + OFF_I0);
  float* m0 = ws + OFF_M0;
  int* i1 = (int*)(ws + OFF_I1);
  short* finbf = msg;                      // alias: msg dead by then

  auto bgemm = [&](const short* A, const short* B, const short* B2, int KS,
                   const float* bias, const float* R, float* C, short* C2,
                   const float* rsc, const float* csc,
                   int M, int N, int K, int ta, float alpha,
                   ll aB, ll bB, ll b2B, ll rB, ll cB, ll c2B,
                   int zb, int act, int nz) {
    bgemm_k<<<dim3(N / 128, M / 128, nz), 256, 0, stream>>>(
        A, B, B2, KS, bias, R, C, C2, rsc, csc, M, N, K, ta, alpha,
        aB, bB, b2B, rB, cB, c2B, zb, act);
  };

  // ---- init ----
  hipMemcpyAsync(stf, desc2dq, (size_t)1572864 * 4, hipMemcpyDeviceToDevice, stream);
  hipMemcpyAsync(stf + 1572864, desc3db, (size_t)1572864 * 4, hipMemcpyDeviceToDevice, stream);
  f2b_k<<<1536, 256, 0, stream>>>(stf, stb, 393216);
  f2b_k<<<768, 256, 0, stream>>>(projw, projw_bf, 196608);
  f2b_k<<<256, 256, 0, stream>>>(mergew, mergew_bf, 65536);
  f2b_k<<<1024, 256, 0, stream>>>(mlp1w, mlp1w_bf, 262144);
  f2b_k<<<512, 256, 0, stream>>>(mlp2w, mlp2w_bf, 131072);
  f2b_k<<<128, 256, 0, stream>>>(gatW, gatw_bf, 32768);
  f2b_k<<<32, 256, 0, stream>>>(finw, finw_bf, 8192);
  gat_prep_k<<<4, 256, 0, stream>>>(gatW, gata, uvec);

  auto attn_layer = [&](int ai, int cross) {
    const short* pw = projw_bf + (ll)ai * 196608;
    const float* pb = projb + (ll)ai * 768;
    if (!cross) {
      // fused q|k|v projection, M=768, batch 4
      bgemm(pw, stb, nullptr, 0, pb, nullptr, nullptr, qkv, nullptr, nullptr,
            768, NPOS, 256, 0, 1.f, 0, 786432, 0, 0, 0, 2359296, 0, 0, 4);
    } else {
      bgemm(pw, stb, nullptr, 0, pb, nullptr, nullptr, qkv, nullptr, nullptr,
            256, NPOS, 256, 0, 1.f, 0, 786432, 0, 0, 0, 2359296, 0, 0, 4);
      bgemm(pw + 65536, stb, nullptr, 0, pb + 256, nullptr, nullptr, qkv + (ll)256 * NPOS,
            nullptr, nullptr,
            512, NPOS, 256, 0, 1.f, 0, 786432, 0, 0, 0, 2359296, 2, 0, 4);
    }
    kv_partial_k<<<dim3(24, 4, 4), 256, 0, stream>>>(qkv, kvp, ksp);
    kv_reduce_k<<<16, 256, 0, stream>>>(kvp, ksp, kvb, ksum);
    attn_out_k<<<dim3(48, 4, 4), 256, 0, stream>>>(qkv, kvb, ksum, obuf);
    bgemm(mergew_bf + (ll)ai * 65536, obuf, nullptr, 0, mergeb + (ll)ai * 256,
          nullptr, nullptr, msg, nullptr, nullptr,
          256, NPOS, 256, 0, 1.f, 0, 786432, 0, 0, 0, 786432, 0, 0, 4);
    // mlp1: B = [state ; msg] split
    bgemm(mlp1w_bf + (ll)ai * 262144, stb, msg, 256, mlp1b + (ll)ai * 512,
          nullptr, nullptr, hid, nullptr, nullptr,
          512, NPOS, 512, 0, 1.f, 0, 786432, 786432, 0, 0, 1572864, 0, 0, 4);
    instnorm_relu_k<<<dim3(512, 4), 256, 0, stream>>>(hid);
    // mlp2 + fp32 residual, in-place state update (fp32 + bf16)
    bgemm(mlp2w_bf + (ll)ai * 131072, hid, nullptr, 0, mlp2b + (ll)ai * 256,
          stf, stf, stb, nullptr, nullptr,
          256, NPOS, 512, 0, 1.f, 0, 1572864, 0, 786432, 786432, 786432, 0, 0, 4);
  };

  auto gat_layer = [&](int gi) {
    const float* uv = uvec + gi * 512;
    gat_edot3_k<<<dim3(12, 8, 2), 256, 0, stream>>>(stb, uv, e3pa, e3pb);
    gat_edot2_k<<<dim3(96, 2, 2), 256, 0, stream>>>(desc2db, uv + 256, e2p);
    gat_att_k<<<dim3(12, 2), 256, 0, stream>>>(e3pa, e3pb, e2p, att);
    gat_g_k<<<dim3(12, 256, 2), 256, 0, stream>>>(stb, desc2db, att, obuf);
    // d3 = elu(W^T @ g), in place on state slots 2..3
    bgemm(gatw_bf + (ll)gi * 65536, obuf, nullptr, 0, nullptr,
          nullptr, stf + (ll)2 * 786432, stb + (ll)2 * 786432, nullptr, nullptr,
          256, NPOS, 256, 1, 1.f, 0, 786432, 0, 0, 786432, 786432, 0, 1, 2);
  };

  int ai = 0, gi = 0;
  for (int r = 0; r < 4; ++r) {
    gat_layer(gi); gi++;
    attn_layer(ai, 0); ai++;   // self
    attn_layer(ai, 1); ai++;   // cross
  }

  // final projection (batch 4) -> bf16 only
  bgemm(finw_bf, stb, nullptr, 0, finb, nullptr, nullptr, finbf, nullptr, nullptr,
        256, NPOS, 256, 0, 1.f, 0, 786432, 0, 0, 0, 786432, 0, 0, 4);
  normcalc_k<<<dim3(48, 4), 256, 0, stream>>>(finbf, svec);

  // scores = 10 * sa[n] sb[m] (mq^T md) -> conf region of d_out
  float* conf = out + 12288;
  bgemm(finbf, finbf, nullptr, 0, nullptr, nullptr, conf, nullptr, svec, svec,
        NPOS, NPOS, 256, 1, 10.f, 786432, 786432, 0, 0, 9437184, 0, 2, 0, 2);

  colstat_part_k<<<dim3(12, 48, 2), 256, 0, stream>>>(conf, pmax, psum);
  colstat_comb_k<<<dim3(12, 2), 256, 0, stream>>>(pmax, psum, cmax, csum);
  rowfix_k<<<dim3(NPOS, 2), 256, 0, stream>>>(conf, cmax, csum, i0, m0);
  colamax_part_k<<<dim3(12, 24), 256, 0, stream>>>(conf, capv, capi);
  colamax_comb_k<<<12, 256, 0, stream>>>(capv, capi, i1);
  match0_k<<<12, 256, 0, stream>>>(i0, m0, i1, out);
  match1_k<<<12, 256, 0, stream>>>(i0, i1, out);
}

// Round 4
// 1946.776 us; speedup vs baseline: 2.2589x; 1.0699x over previous
//
#include <hip/hip_runtime.h>
#include <hip/hip_bf16.h>
#include <math.h>

typedef long long ll;
typedef __attribute__((ext_vector_type(8))) short s8v;
typedef __attribute__((ext_vector_type(4))) float f4v;

#define NPOS 3072
// state z layout: [0]=dq_b0 [1]=dq_b1 [2]=d3_b0 [3]=d3_b1
// ALL activations position-major: [z][n][c]

// ---------------- workspace offsets (floats) ----------------
#define OFF_STF   0LL          /* fp32 state [4][3072][256] */
#define OFF_STB   3145728LL    /* bf16 state (shorts) */
#define OFF_QKV   4718592LL    /* bf16 [4][3072][768] shorts */
#define OFF_MSG   9437184LL    /* bf16 [4][3072][256] shorts; finbf alias */
#define OFF_HID   11010048LL   /* bf16 [4][3072][512] shorts; obuf/g = lower, kvp = upper */
#define OFF_WBF   14155776LL   /* bf16 weights, 5,570,560 shorts */
#define OFF_PBP   16941056LL   /* permuted projb fp32 [8][768] */
#define OFF_KV    16947200LL   /* fp32 [16][4096] */
#define OFF_KSUM  17012736LL
#define OFF_KSP   17013760LL   /* [16][12][64] */
#define OFF_UVEC  17026048LL
#define OFF_E2ALL 17028096LL   /* [4][2][24576] */
#define OFF_ATT   17224704LL   /* [2][3072][9] */
#define OFF_SVEC  17280000LL   /* [4][3072] */
#define OFF_INP   17292288LL   /* instnorm partials [4][8][8][64][2] */
#define OFF_PMAX  17300480LL
#define OFF_PSUM  17595392LL
#define OFF_CMAX  17890304LL
#define OFF_CSUM  17896448LL
#define OFF_CAPV  17902592LL
#define OFF_CAPI  17976320LL
#define OFF_I0    18050048LL
#define OFF_M0    18053120LL
#define OFF_I1    18056192LL

__device__ __forceinline__ float b2f(short s) {
  union { unsigned u; float f; } c;
  c.u = ((unsigned)(unsigned short)s) << 16;
  return c.f;
}
__device__ __forceinline__ short f2b(float f) {
  __hip_bfloat16 h = __float2bfloat16(f);
  union { __hip_bfloat16 h; short s; } c; c.h = h; return c.s;
}
__device__ __forceinline__ unsigned pk2(float a, float b) {
  return (unsigned)(unsigned short)f2b(a) | ((unsigned)(unsigned short)f2b(b) << 16);
}
__device__ __forceinline__ float waveSum(float v) {
#pragma unroll
  for (int off = 32; off > 0; off >>= 1) v += __shfl_down(v, off);
  return v;
}

// ------------------------------------------------------------------
// bf16 MFMA GEMM, position-major: C[i][j] = act(alpha*sum_k A[i][k]B[j][k]
//   (*rs[i]*cs[j]) + bias[j] + R[i][j])
// A: activations [I][K] k-contiguous, z-batched (za offset), optional split
// along k at KS (A2). B: weights [J][K] k-contiguous (zbo offset, bB=0 for
// shared weights). Both staged with direct uint4 copies (no repack).
// Tile 128x128, 4 waves, 4x4 frags of 16x16x32. LDS stride 40 shorts.
// ------------------------------------------------------------------
__global__ __launch_bounds__(256) void bgemm_k(
    const short* __restrict__ A, const short* __restrict__ A2, int KS,
    int lda, int lda2,
    const short* __restrict__ B,
    const float* __restrict__ bias, const float* __restrict__ R,
    float* __restrict__ C, short* __restrict__ C2,
    const float* __restrict__ rs, const float* __restrict__ cs,
    int K, int ldc, float alpha,
    ll aB, ll a2B, ll bB, ll rB, ll cB, ll c2B,
    int za, int zbo, int act)
{
  __shared__ __align__(16) short As[128 * 40];
  __shared__ __align__(16) short Bs[128 * 40];
  const int z = blockIdx.z;
  const int zA = (z + za) & 3, zB = (z + zbo) & 3;
  const int j0 = blockIdx.x * 128, i0 = blockIdx.y * 128;
  const int t = threadIdx.x;
  const int lane = t & 63, w = t >> 6;
  const int wi = (w & 1) * 64, wj = (w >> 1) * 64;
  const int fr = lane & 15;
  const int k8 = (lane >> 4) * 8;
  const int r4 = (lane >> 4) * 4;
  const short* Bb = B + (ll)zB * bB;

  f4v acc[4][4];
#pragma unroll
  for (int i = 0; i < 4; ++i)
#pragma unroll
    for (int j = 0; j < 4; ++j) acc[i][j] = (f4v)0.f;

  for (int k0 = 0; k0 < K; k0 += 32) {
    const short* Asrc; int kk0, ldax;
    if (A2 && k0 >= KS) { Asrc = A2 + (ll)zA * a2B; kk0 = k0 - KS; ldax = lda2; }
    else { Asrc = A + (ll)zA * aB; kk0 = k0; ldax = lda; }
#pragma unroll
    for (int i = 0; i < 2; ++i) {
      int cc = t + i * 256;
      int r = cc >> 2, kq = (cc & 3) * 8;
      *(uint4*)(As + r * 40 + kq) =
          *(const uint4*)(Asrc + (ll)(i0 + r) * ldax + kk0 + kq);
    }
#pragma unroll
    for (int i = 0; i < 2; ++i) {
      int cc = t + i * 256;
      int r = cc >> 2, kq = (cc & 3) * 8;
      *(uint4*)(Bs + r * 40 + kq) =
          *(const uint4*)(Bb + (ll)(j0 + r) * K + k0 + kq);
    }
    __syncthreads();
    s8v af[4], bfr[4];
#pragma unroll
    for (int im = 0; im < 4; ++im)
      af[im] = *(const s8v*)(As + (wi + im * 16 + fr) * 40 + k8);
#pragma unroll
    for (int in = 0; in < 4; ++in)
      bfr[in] = *(const s8v*)(Bs + (wj + in * 16 + fr) * 40 + k8);
#pragma unroll
    for (int im = 0; im < 4; ++im)
#pragma unroll
      for (int in = 0; in < 4; ++in)
        acc[im][in] = __builtin_amdgcn_mfma_f32_16x16x32_bf16(
            af[im], bfr[in], acc[im][in], 0, 0, 0);
    __syncthreads();
  }

  float bv4[4], cv4[4];
#pragma unroll
  for (int in = 0; in < 4; ++in) {
    int j = j0 + wj + in * 16 + fr;
    bv4[in] = bias ? bias[j] : 0.f;
    cv4[in] = cs ? cs[(ll)zB * NPOS + j] : 1.f;
  }
#pragma unroll
  for (int im = 0; im < 4; ++im) {
#pragma unroll
    for (int r = 0; r < 4; ++r) {
      int i = i0 + wi + im * 16 + r4 + r;
      float rsv = rs ? rs[(ll)z * NPOS + i] : 1.f;
      ll rowo = (ll)i * ldc;
#pragma unroll
      for (int in = 0; in < 4; ++in) {
        int j = j0 + wj + in * 16 + fr;
        float v = acc[im][in][r] * alpha;
        if (rs) v = v * rsv * cv4[in];
        v += bv4[in];
        ll off = rowo + j;
        if (R) v += R[(ll)z * rB + off];
        if (act) v = v > 0.f ? v : (expf(v) - 1.f);
        if (C) C[(ll)z * cB + off] = v;
        if (C2) C2[(ll)z * c2B + off] = f2b(v);
      }
    }
  }
}

// ---------------- init: transpose inputs [c][n] -> [n][c] ----------------
__global__ void transpose_in_k(const float* __restrict__ dq, const float* __restrict__ d3,
                               float* __restrict__ stf, short* __restrict__ stb)
{
  __shared__ float tile[64][65];
  int z = blockIdx.z;
  const float* src = (z < 2) ? dq + (ll)z * 786432 : d3 + (ll)(z - 2) * 786432;
  int c0 = blockIdx.y * 64, n0 = blockIdx.x * 64;
  int t = threadIdx.x;
  int nj = t & 63, q = t >> 6;
#pragma unroll
  for (int i = 0; i < 16; ++i) {
    int ci = q + i * 4;
    tile[ci][nj] = src[(ll)(c0 + ci) * NPOS + n0 + nj];
  }
  __syncthreads();
  int cj = t & 63;
#pragma unroll
  for (int i = 0; i < 16; ++i) {
    int ni = q + i * 4;
    float v = tile[cj][ni];
    ll o = (ll)z * 786432 + (ll)(n0 + ni) * 256 + c0 + cj;
    stf[o] = v;
    stb[o] = f2b(v);
  }
}

// ---------------- weight conversions ----------------
__global__ void f2b_k(const float* __restrict__ src, short* __restrict__ dst, int n8)
{
  int gi = blockIdx.x * 256 + threadIdx.x;
  if (gi >= n8) return;
  ll e = (ll)gi * 8;
  float4 a = *(const float4*)(src + e);
  float4 b = *(const float4*)(src + e + 4);
  uint4 o;
  o.x = pk2(a.x, a.y); o.y = pk2(a.z, a.w);
  o.z = pk2(b.x, b.y); o.w = pk2(b.z, b.w);
  *(uint4*)(dst + e) = o;
}

// projw rows permuted: new row sec*256 + (h*64+dh) <- old row sec*256 + (dh*4+h)
__global__ void projw_perm_k(const float* __restrict__ src, short* __restrict__ dst)
{
  int idx = blockIdx.x * 256 + threadIdx.x;   // 8*768*256
  int c = idx & 255;
  int row = (idx >> 8) % 768;
  int ai = (idx >> 8) / 768;
  int sec = row >> 8;
  int p = row & 255;
  int o = (p & 63) * 4 + (p >> 6);
  dst[idx] = f2b(src[(((ll)ai * 3 + sec) * 256 + o) * 256 + c]);
}

__global__ void pbp_k(const float* __restrict__ pb, float* __restrict__ pbp)
{
  int idx = blockIdx.x * 256 + threadIdx.x;   // 6144
  int row = idx % 768, ai = idx / 768;
  int sec = row >> 8;
  int p = row & 255;
  int o = (p & 63) * 4 + (p >> 6);
  pbp[idx] = pb[ai * 768 + (sec << 8) + o];
}

// mergew columns permuted: new col h*64+dh <- old col dh*4+h
__global__ void mergew_perm_k(const float* __restrict__ src, short* __restrict__ dst)
{
  int idx = blockIdx.x * 256 + threadIdx.x;   // 8*256*256
  int p = idx & 255;
  int o = (idx >> 8) & 255;
  int ai = idx >> 16;
  int cin = (p & 63) * 4 + (p >> 6);
  dst[idx] = f2b(src[(ll)ai * 65536 + o * 256 + cin]);
}

// gatW transposed: dst[gi][o][d] = src[gi][d][o]
__global__ void gatw_t_k(const float* __restrict__ src, short* __restrict__ dst)
{
  int idx = blockIdx.x * 256 + threadIdx.x;   // 4*256*256
  int d = idx & 255;
  int o = (idx >> 8) & 255;
  int gi = idx >> 16;
  dst[idx] = f2b(src[(ll)gi * 65536 + d * 256 + o]);
}

// ---------------- GAT ----------------
__global__ void gat_prep_k(const float* __restrict__ gatW, const float* __restrict__ gata,
                           float* __restrict__ uvec)
{
  int gi = blockIdx.x; int d = threadIdx.x;
  const float* W = gatW + (ll)gi * 65536;
  const float* a = gata + gi * 512;
  float u0 = 0.f, u1 = 0.f;
  for (int o = 0; o < 256; ++o) {
    float w = W[d * 256 + o];
    u0 = fmaf(w, a[o], u0);
    u1 = fmaf(w, a[256 + o], u1);
  }
  uvec[gi * 512 + d] = u0;
  uvec[gi * 512 + 256 + d] = u1;
}

// all 4 layers' e2 in one pass over d2db. grid (96, 2)
__global__ void e2all_k(const float* __restrict__ d2db, const float* __restrict__ uvec,
                        float* __restrict__ e2all)
{
  __shared__ float us[1024];
  int t = threadIdx.x;
  for (int idx = t; idx < 1024; idx += 256)
    us[idx] = uvec[(idx >> 8) * 512 + 256 + (idx & 255)];
  __syncthreads();
  int m = blockIdx.x * 256 + t;
  int b = blockIdx.y;
  const float* xb = d2db + (ll)b * 6291456;
  float a[4] = {};
  for (int c = 0; c < 256; ++c) {
    float v = xb[(ll)c * 24576 + m];
#pragma unroll
    for (int g = 0; g < 4; ++g) a[g] = fmaf(v, us[g * 256 + c], a[g]);
  }
#pragma unroll
  for (int g = 0; g < 4; ++g) e2all[((ll)g * 2 + b) * 24576 + m] = a[g];
}

// fused e3 dots + leaky + softmax -> att[b][n][9]. grid (12, 2)
__global__ void gat_att_k(const short* __restrict__ stb, const float* __restrict__ uvec,
                          const float* __restrict__ e2all, float* __restrict__ att, int gi)
{
  __shared__ float ush[512];
  int t = threadIdx.x;
  for (int idx = t; idx < 512; idx += 256) ush[idx] = uvec[gi * 512 + idx];
  __syncthreads();
  int n = blockIdx.x * 256 + t;
  int b = blockIdx.y;
  const short* xr = stb + (ll)(2 + b) * 786432 + (ll)n * 256;
  float a0 = 0.f, a1 = 0.f;
#pragma unroll 8
  for (int i = 0; i < 32; ++i) {
    s8v v8 = *(const s8v*)(xr + i * 8);
#pragma unroll
    for (int j = 0; j < 8; ++j) {
      float v = b2f(v8[j]);
      a0 = fmaf(v, ush[i * 8 + j], a0);
      a1 = fmaf(v, ush[256 + i * 8 + j], a1);
    }
  }
  float e[9];
  e[0] = a0 + a1;
  const float* e2b = e2all + ((ll)gi * 2 + b) * 24576 + (ll)n * 8;
#pragma unroll
  for (int l = 0; l < 8; ++l) e[l + 1] = a0 + e2b[l];
  float mx = -3.4e38f;
#pragma unroll
  for (int l = 0; l < 9; ++l) {
    e[l] = e[l] >= 0.f ? e[l] : 0.2f * e[l];
    mx = fmaxf(mx, e[l]);
  }
  float s = 0.f;
#pragma unroll
  for (int l = 0; l < 9; ++l) { e[l] = expf(e[l] - mx); s += e[l]; }
  float inv = 1.f / s;
  float* ao = att + ((ll)b * NPOS + n) * 9;
#pragma unroll
  for (int l = 0; l < 9; ++l) ao[l] = e[l] * inv;
}

// g[b][n][c] = at0*d3[n][c] + sum_l at[l+1]*d2db[b][c][n*8+l]
// tile 64n x 64c via LDS transpose. grid (48, 4, 2)
__global__ __launch_bounds__(256) void gat_g_k(
    const short* __restrict__ stb, const float* __restrict__ d2db,
    const float* __restrict__ att, short* __restrict__ g)
{
  __shared__ float attw[576];
  __shared__ float gtile[64 * 69];
  const int n0 = blockIdx.x * 64, c0 = blockIdx.y * 64, b = blockIdx.z;
  const int t = threadIdx.x;
  for (int idx = t; idx < 576; idx += 256)
    attw[idx] = att[((ll)b * NPOS + n0) * 9 + idx];
  __syncthreads();
  const int nl = t >> 2, l2 = (t & 3) * 2;
  for (int cc = 0; cc < 64; ++cc) {
    const float* src = d2db + ((ll)b * 256 + c0 + cc) * 24576 + (ll)n0 * 8;
    float2 v = *(const float2*)(src + t * 2);
    float p = v.x * attw[nl * 9 + 1 + l2] + v.y * attw[nl * 9 + 2 + l2];
    p += __shfl_xor(p, 1);
    p += __shfl_xor(p, 2);
    if ((t & 3) == 0) gtile[nl * 69 + cc] = p;
  }
  __syncthreads();
#pragma unroll
  for (int i = 0; i < 4; ++i) {
    int n = (t >> 4) + i * 16;
    int cp = (t & 15) * 4;
    float at0 = attw[n * 9];
    const short* dr = stb + (ll)(2 + b) * 786432 + (ll)(n0 + n) * 256 + c0 + cp;
    uint2 dv = *(const uint2*)dr;
    float d0 = b2f((short)(dv.x & 0xffff)), d1 = b2f((short)(dv.x >> 16));
    float d2 = b2f((short)(dv.y & 0xffff)), d3v = b2f((short)(dv.y >> 16));
    uint2 ov;
    ov.x = pk2(gtile[n * 69 + cp] + at0 * d0, gtile[n * 69 + cp + 1] + at0 * d1);
    ov.y = pk2(gtile[n * 69 + cp + 2] + at0 * d2, gtile[n * 69 + cp + 3] + at0 * d3v);
    *(uint2*)(g + (ll)b * 786432 + (ll)(n0 + n) * 256 + c0 + cp) = ov;
  }
}

// ---------------- linear attention (h-planar channels) ----------------
// qkv [z][n][768]: q at c=h*64+dh, k at 256+h*64+d, v at 512+h*64+d
__global__ __launch_bounds__(256) void kv_partial_k(
    const short* __restrict__ qkv, float* __restrict__ kvp, float* __restrict__ ksp)
{
  __shared__ float ks[32][66];
  __shared__ float vs[32][66];
  const int p = blockIdx.x, h = blockIdx.y, z = blockIdx.z;
  const short* base = qkv + (ll)z * 2359296;
  const int t = threadIdx.x;
  const int tq = (t >> 4) * 4, tk = (t & 15) * 4;
  const int ml = t >> 3, d8 = (t & 7) * 8;
  float acc[4][4] = {};
  float ksl = 0.f;
  for (int sub = 0; sub < 8; ++sub) {
    int m0 = p * 256 + sub * 32;
    {
      const short* kr = base + (ll)(m0 + ml) * 768 + 256 + h * 64 + d8;
      s8v k8 = *(const s8v*)kr;
      s8v v8 = *(const s8v*)(kr + 256);
#pragma unroll
      for (int j = 0; j < 8; ++j) {
        float kvv = b2f(k8[j]);
        ks[ml][d8 + j] = kvv > 0.f ? kvv + 1.f : expf(kvv);  // elu+1
        vs[ml][d8 + j] = b2f(v8[j]);
      }
    }
    __syncthreads();
#pragma unroll 8
    for (int mm = 0; mm < 32; ++mm) {
      float vv[4], kk[4];
#pragma unroll
      for (int i = 0; i < 4; ++i) { vv[i] = vs[mm][tq + i]; kk[i] = ks[mm][tk + i]; }
#pragma unroll
      for (int i = 0; i < 4; ++i)
#pragma unroll
        for (int j = 0; j < 4; ++j)
          acc[i][j] = fmaf(vv[i], kk[j], acc[i][j]);
    }
    if (t < 64) {
#pragma unroll 8
      for (int mm = 0; mm < 32; ++mm) ksl += ks[mm][t];
    }
    __syncthreads();
  }
  ll o = (((ll)z * 4 + h) * 12 + p) * 4096;
#pragma unroll
  for (int i = 0; i < 4; ++i)
    *(float4*)(kvp + o + (tq + i) * 64 + tk) =
        make_float4(acc[i][0], acc[i][1], acc[i][2], acc[i][3]);
  if (t < 64) ksp[(((ll)z * 4 + h) * 12 + p) * 64 + t] = ksl;
}

__global__ void kv_reduce_k(const float* __restrict__ kvp, const float* __restrict__ ksp,
                            float* __restrict__ kv, float* __restrict__ ksum)
{
  int bh = blockIdx.x; int t = threadIdx.x;
  for (int e = t; e < 4096; e += 256) {
    float s = 0.f;
    for (int p = 0; p < 12; ++p) s += kvp[((ll)bh * 12 + p) * 4096 + e];
    kv[(ll)bh * 4096 + (ll)(e & 63) * 64 + (e >> 6)] = s;  // -> [d][qd]
  }
  if (t < 64) {
    float s = 0.f;
    for (int p = 0; p < 12; ++p) s += ksp[((ll)bh * 12 + p) * 64 + t];
    ksum[bh * 64 + t] = s;
  }
}

__global__ __launch_bounds__(256) void attn_out_k(
    const short* __restrict__ qkv, const float* __restrict__ kv,
    const float* __restrict__ ksum, short* __restrict__ obuf)
{
  __shared__ float qt[64][67];
  __shared__ float kvT[64][66];
  __shared__ float zsh[64];
  __shared__ float kss[64];
  const int n0 = blockIdx.x * 64, h = blockIdx.y, z = blockIdx.z;
  const int t = threadIdx.x;
  {
    int nl = t >> 3, d8 = (t & 7) * 8;
    const short* qr0 = qkv + (ll)z * 2359296 + (ll)(n0 + nl) * 768 + h * 64 + d8;
#pragma unroll
    for (int i = 0; i < 2; ++i) {
      const short* qr = qr0 + (ll)i * 32 * 768;
      s8v q8 = *(const s8v*)qr;
#pragma unroll
      for (int j = 0; j < 8; ++j) {
        float q = b2f(q8[j]);
        qt[nl + i * 32][d8 + j] = q > 0.f ? q + 1.f : expf(q);
      }
    }
  }
  {
    const float* kvb = kv + (ll)(z * 4 + h) * 4096;
#pragma unroll
    for (int i = 0; i < 16; ++i) {
      int idx = t + i * 256;
      kvT[idx >> 6][idx & 63] = kvb[idx];
    }
  }
  if (t < 64) kss[t] = ksum[(z * 4 + h) * 64 + t];
  __syncthreads();
  if (t < 64) {
    float s = 0.f;
    for (int d = 0; d < 64; ++d) s = fmaf(qt[t][d], kss[d], s);
    zsh[t] = 1.f / (s + 1e-6f);
  }
  __syncthreads();
  const int tn = t >> 4, tj = t & 15;
  float acc[4][4] = {};
  for (int d = 0; d < 64; ++d) {
    float av[4], bv[4];
#pragma unroll
    for (int i = 0; i < 4; ++i) av[i] = qt[tn * 4 + i][d];
    *(float4*)bv = *(const float4*)&kvT[d][tj * 4];
#pragma unroll
    for (int i = 0; i < 4; ++i)
#pragma unroll
      for (int j = 0; j < 4; ++j)
        acc[i][j] = fmaf(av[i], bv[j], acc[i][j]);
  }
#pragma unroll
  for (int i = 0; i < 4; ++i) {
    int n = n0 + tn * 4 + i;
    float zv = zsh[tn * 4 + i];
    uint2 o;
    o.x = pk2(acc[i][0] * zv, acc[i][1] * zv);
    o.y = pk2(acc[i][2] * zv, acc[i][3] * zv);
    *(uint2*)(obuf + (ll)z * 786432 + (ll)n * 256 + h * 64 + tj * 4) = o;
  }
}

// ---------------- instnorm (+relu), column stats over n ----------------
__global__ void in_part_k(const short* __restrict__ hid, float* __restrict__ part)
{
  int z = blockIdx.z, cg = blockIdx.y, nc = blockIdx.x;
  int t = threadIdx.x;
  int c = cg * 64 + (t & 63);
  const short* base = hid + (ll)z * 1572864 + (ll)(nc * 384 + (t >> 6)) * 512 + c;
  float s = 0.f, q = 0.f;
#pragma unroll 4
  for (int i = 0; i < 96; ++i) {
    float v = b2f(base[(ll)i * 2048]);
    s += v; q = fmaf(v, v, q);
  }
  __shared__ float rs_[4][64], rq_[4][64];
  rs_[t >> 6][t & 63] = s; rq_[t >> 6][t & 63] = q;
  __syncthreads();
  if (t < 64) {
    s = rs_[0][t] + rs_[1][t] + rs_[2][t] + rs_[3][t];
    q = rq_[0][t] + rq_[1][t] + rq_[2][t] + rq_[3][t];
    ll o = ((((ll)z * 8 + cg) * 8 + nc) * 64 + t) * 2;
    part[o] = s; part[o + 1] = q;
  }
}

__global__ void in_apply_k(short* __restrict__ hid, const float* __restrict__ part)
{
  int z = blockIdx.z, cg = blockIdx.y, nc = blockIdx.x;
  int t = threadIdx.x;
  int c = cg * 64 + (t & 63);
  float s = 0.f, q = 0.f;
#pragma unroll
  for (int p = 0; p < 8; ++p) {
    ll o = ((((ll)z * 8 + cg) * 8 + p) * 64 + (t & 63)) * 2;
    s += part[o]; q += part[o + 1];
  }
  float mu = s * (1.f / NPOS);
  float var = q * (1.f / NPOS) - mu * mu;
  float rsig = rsqrtf(fmaxf(var, 0.f) + 1e-5f);
  short* base = hid + (ll)z * 1572864 + (ll)(nc * 384 + (t >> 6)) * 512 + c;
#pragma unroll 4
  for (int i = 0; i < 96; ++i) {
    float v = (b2f(base[(ll)i * 2048]) - mu) * rsig;
    base[(ll)i * 2048] = f2b(v > 0.f ? v : 0.f);
  }
}

// ---------------- final epilogue ----------------
__global__ void normcalc_k(const short* __restrict__ f, float* __restrict__ svec)
{
  int n = blockIdx.x * 256 + threadIdx.x;
  int z = blockIdx.y;
  const short* r = f + (ll)z * 786432 + (ll)n * 256;
  float s = 0.f;
#pragma unroll 8
  for (int i = 0; i < 32; ++i) {
    s8v v8 = *(const s8v*)(r + i * 8);
#pragma unroll
    for (int j = 0; j < 8; ++j) { float v = b2f(v8[j]); s = fmaf(v, v, s); }
  }
  svec[z * NPOS + n] = 1.f / fmaxf(sqrtf(s), 1e-12f);
}

__global__ void colstat_part_k(const float* __restrict__ S,
                               float* __restrict__ pmax, float* __restrict__ psum)
{
  int m = blockIdx.x * 256 + threadIdx.x;
  int chunk = blockIdx.y; int b = blockIdx.z;
  const float* base = S + (ll)b * 9437184 + m;
  float mx = -3.4e38f, s = 0.f;
  int n0 = chunk * 64;
  for (int n = n0; n < n0 + 64; ++n) {
    float v = base[(ll)n * NPOS];
    if (v > mx) { s = s * expf(mx - v) + 1.f; mx = v; }
    else s += expf(v - mx);
  }
  ll o = ((ll)b * 48 + chunk) * NPOS + m;
  pmax[o] = mx; psum[o] = s;
}

__global__ void colstat_comb_k(const float* __restrict__ pmax, const float* __restrict__ psum,
                               float* __restrict__ cmax, float* __restrict__ csum)
{
  int m = blockIdx.x * 256 + threadIdx.x; int b = blockIdx.y;
  float M = -3.4e38f;
  for (int c = 0; c < 48; ++c) M = fmaxf(M, pmax[((ll)b * 48 + c) * NPOS + m]);
  float s = 0.f;
  for (int c = 0; c < 48; ++c)
    s += psum[((ll)b * 48 + c) * NPOS + m] * expf(pmax[((ll)b * 48 + c) * NPOS + m] - M);
  cmax[b * NPOS + m] = M; csum[b * NPOS + m] = s;
}

__global__ __launch_bounds__(256) void rowfix_k(
    float* __restrict__ S, const float* __restrict__ cmax, const float* __restrict__ csum,
    int* __restrict__ i0, float* __restrict__ m0)
{
  int n = blockIdx.x, b = blockIdx.y, t = threadIdx.x;
  float* row = S + (ll)b * 9437184 + (ll)n * NPOS;
  __shared__ float red[4];
  float v[12];
  float mx = -3.4e38f;
#pragma unroll
  for (int i = 0; i < 12; ++i) { v[i] = row[t + i * 256]; mx = fmaxf(mx, v[i]); }
#pragma unroll
  for (int off = 32; off > 0; off >>= 1) mx = fmaxf(mx, __shfl_down(mx, off));
  if ((t & 63) == 0) red[t >> 6] = mx;
  __syncthreads();
  float rm = fmaxf(fmaxf(red[0], red[1]), fmaxf(red[2], red[3]));
  __syncthreads();
  float s = 0.f;
#pragma unroll
  for (int i = 0; i < 12; ++i) s += expf(v[i] - rm);
  s = waveSum(s);
  if ((t & 63) == 0) red[t >> 6] = s;
  __syncthreads();
  float irs = 1.f / (red[0] + red[1] + red[2] + red[3]);
  float bv = -1.f; int bi = 0;
#pragma unroll
  for (int i = 0; i < 12; ++i) {
    int m = t + i * 256;
    float f = expf(2.f * v[i] - rm - cmax[b * NPOS + m]) * irs / csum[b * NPOS + m];
    row[m] = f;
    if (f > bv) { bv = f; bi = m; }
  }
  if (b == 0) {
#pragma unroll
    for (int off = 32; off > 0; off >>= 1) {
      float ov = __shfl_down(bv, off);
      int oi = __shfl_down(bi, off);
      if (ov > bv || (ov == bv && oi < bi)) { bv = ov; bi = oi; }
    }
    __shared__ float rv[4]; __shared__ int ri[4];
    if ((t & 63) == 0) { rv[t >> 6] = bv; ri[t >> 6] = bi; }
    __syncthreads();
    if (t == 0) {
      for (int w = 1; w < 4; ++w)
        if (rv[w] > bv || (rv[w] == bv && ri[w] < bi)) { bv = rv[w]; bi = ri[w]; }
      i0[n] = bi; m0[n] = bv;
    }
  }
}

__global__ void colamax_part_k(const float* __restrict__ Cf,
                               float* __restrict__ capv, int* __restrict__ capi)
{
  int m = blockIdx.x * 256 + threadIdx.x;
  int n0 = blockIdx.y * 128;
  float bv = -1.f; int bi = 0;
  for (int n = n0; n < n0 + 128; ++n) {
    float f = Cf[(ll)n * NPOS + m];
    if (f > bv) { bv = f; bi = n; }
  }
  capv[blockIdx.y * NPOS + m] = bv;
  capi[blockIdx.y * NPOS + m] = bi;
}

__global__ void colamax_comb_k(const float* __restrict__ capv, const int* __restrict__ capi,
                               int* __restrict__ i1)
{
  int m = blockIdx.x * 256 + threadIdx.x;
  float bv = -1.f; int bi = 0;
  for (int c = 0; c < 24; ++c) {
    float v = capv[c * NPOS + m];
    if (v > bv) { bv = v; bi = capi[c * NPOS + m]; }
  }
  i1[m] = bi;
}

__global__ void match0_k(const int* __restrict__ i0, const float* __restrict__ m0,
                         const int* __restrict__ i1, float* __restrict__ out)
{
  int n = blockIdx.x * 256 + threadIdx.x;
  int j = i0[n];
  bool mut = (i1[j] == n);
  float ms0 = mut ? m0[n] : 0.f;
  bool valid = mut && (ms0 > 0.2f);
  out[n] = valid ? (float)j : -1.f;
  out[6144 + n] = ms0;
}

__global__ void match1_k(const int* __restrict__ i0, const int* __restrict__ i1,
                         float* __restrict__ out)
{
  int m = blockIdx.x * 256 + threadIdx.x;
  int j = i1[m];
  bool mut = (i0[j] == m);
  float ms0v = out[6144 + j];
  float ind0v = out[j];
  float ms1 = mut ? ms0v : 0.f;
  bool valid1 = mut && (ind0v >= 0.f);
  out[3072 + m] = valid1 ? (float)j : -1.f;
  out[9216 + m] = ms1;
}

// ------------------------------------------------------------------
extern "C" void kernel_launch(void* const* d_in, const int* in_sizes, int n_in,
                              void* d_out, int out_size, void* d_ws, size_t ws_size,
                              hipStream_t stream)
{
  const float* desc2dq = (const float*)d_in[0];
  const float* desc3db = (const float*)d_in[1];
  const float* desc2db = (const float*)d_in[2];
  const float* projw = (const float*)d_in[3];
  const float* projb = (const float*)d_in[4];
  const float* mergew = (const float*)d_in[5];
  const float* mergeb = (const float*)d_in[6];
  const float* mlp1w = (const float*)d_in[7];
  const float* mlp1b = (const float*)d_in[8];
  const float* mlp2w = (const float*)d_in[9];
  const float* mlp2b = (const float*)d_in[10];
  const float* gatW = (const float*)d_in[11];
  const float* gata = (const float*)d_in[12];
  const float* finw = (const float*)d_in[13];
  const float* finb = (const float*)d_in[14];

  float* ws = (float*)d_ws;
  float* out = (float*)d_out;

  float* stf = ws + OFF_STF;
  short* stb = (short*)(ws + OFF_STB);
  short* qkv = (short*)(ws + OFF_QKV);
  short* msg = (short*)(ws + OFF_MSG);
  short* hid = (short*)(ws + OFF_HID);
  short* obuf = hid;                       // alias (lower half of hid)
  float* kvp = ws + OFF_HID + 1572864;     // alias (upper half of hid)
  short* wbf = (short*)(ws + OFF_WBF);
  short* projw_bf = wbf;
  short* mergew_bf = wbf + 1572864;
  short* mlp1w_bf = wbf + 2097152;
  short* mlp2w_bf = wbf + 4194304;
  short* gatwT_bf = wbf + 5242880;
  short* finw_bf = wbf + 5505024;
  float* pbp = ws + OFF_PBP;
  float* kvb = ws + OFF_KV;
  float* ksum = ws + OFF_KSUM;
  float* ksp = ws + OFF_KSP;
  float* uvec = ws + OFF_UVEC;
  float* e2all = ws + OFF_E2ALL;
  float* att = ws + OFF_ATT;
  float* svec = ws + OFF_SVEC;
  float* inp = ws + OFF_INP;
  float* pmax = ws + OFF_PMAX;
  float* psum = ws + OFF_PSUM;
  float* cmax = ws + OFF_CMAX;
  float* csum = ws + OFF_CSUM;
  float* capv = ws + OFF_CAPV;
  int* capi = (int*)(ws + OFF_CAPI);
  int* i0 = (int*)(ws + OFF_I0);
  float* m0 = ws + OFF_M0;
  int* i1 = (int*)(ws + OFF_I1);
  short* finbf = msg;                      // alias (msg dead by then)

  auto bgemm = [&](const short* A, const short* A2, int KS, int lda, int lda2,
                   const short* B, const float* bias, const float* R,
                   float* C, short* C2, const float* rsc, const float* csc,
                   int J, int K, int ldc, float alpha,
                   ll aB, ll a2B, ll bB, ll rB, ll cB, ll c2B,
                   int za, int zbo, int act, int nz) {
    bgemm_k<<<dim3(J / 128, 24, nz), 256, 0, stream>>>(
        A, A2, KS, lda, lda2, B, bias, R, C, C2, rsc, csc,
        K, ldc, alpha, aB, a2B, bB, rB, cB, c2B, za, zbo, act);
  };

  // ---- init ----
  transpose_in_k<<<dim3(48, 4, 4), 256, 0, stream>>>(desc2dq, desc3db, stf, stb);
  projw_perm_k<<<6144, 256, 0, stream>>>(projw, projw_bf);
  pbp_k<<<24, 256, 0, stream>>>(projb, pbp);
  mergew_perm_k<<<2048, 256, 0, stream>>>(mergew, mergew_bf);
  f2b_k<<<1024, 256, 0, stream>>>(mlp1w, mlp1w_bf, 262144);
  f2b_k<<<512, 256, 0, stream>>>(mlp2w, mlp2w_bf, 131072);
  gatw_t_k<<<1024, 256, 0, stream>>>(gatW, gatwT_bf);
  f2b_k<<<32, 256, 0, stream>>>(finw, finw_bf, 8192);
  gat_prep_k<<<4, 256, 0, stream>>>(gatW, gata, uvec);
  e2all_k<<<dim3(96, 2), 256, 0, stream>>>(desc2db, uvec, e2all);

  auto attn_layer = [&](int ai, int cross) {
    const short* pw = projw_bf + (ll)ai * 196608;
    const float* pb = pbp + (ll)ai * 768;
    if (!cross) {
      bgemm(stb, nullptr, 0, 256, 0, pw, pb, nullptr, nullptr, qkv, nullptr, nullptr,
            768, 256, 768, 1.f, 786432, 0, 0, 0, 0, 2359296, 0, 0, 0, 4);
    } else {
      bgemm(stb, nullptr, 0, 256, 0, pw, pb, nullptr, nullptr, qkv, nullptr, nullptr,
            256, 256, 768, 1.f, 786432, 0, 0, 0, 0, 2359296, 0, 0, 0, 4);
      bgemm(stb, nullptr, 0, 256, 0, pw + 65536, pb + 256, nullptr, nullptr, qkv + 256,
            nullptr, nullptr,
            512, 256, 768, 1.f, 786432, 0, 0, 0, 0, 2359296, 2, 0, 0, 4);
    }
    kv_partial_k<<<dim3(12, 4, 4), 256, 0, stream>>>(qkv, kvp, ksp);
    kv_reduce_k<<<16, 256, 0, stream>>>(kvp, ksp, kvb, ksum);
    attn_out_k<<<dim3(48, 4, 4), 256, 0, stream>>>(qkv, kvb, ksum, obuf);
    bgemm(obuf, nullptr, 0, 256, 0, mergew_bf + (ll)ai * 65536, mergeb + (ll)ai * 256,
          nullptr, nullptr, msg, nullptr, nullptr,
          256, 256, 256, 1.f, 786432, 0, 0, 0, 0, 786432, 0, 0, 0, 4);
    bgemm(stb, msg, 256, 256, 256, mlp1w_bf + (ll)ai * 262144, mlp1b + (ll)ai * 512,
          nullptr, nullptr, hid, nullptr, nullptr,
          512, 512, 512, 1.f, 786432, 786432, 0, 0, 0, 1572864, 0, 0, 0, 4);
    in_part_k<<<dim3(8, 8, 4), 256, 0, stream>>>(hid, inp);
    in_apply_k<<<dim3(8, 8, 4), 256, 0, stream>>>(hid, inp);
    bgemm(hid, nullptr, 0, 512, 0, mlp2w_bf + (ll)ai * 131072, mlp2b + (ll)ai * 256,
          stf, stf, stb, nullptr, nullptr,
          256, 512, 256, 1.f, 1572864, 0, 0, 786432, 786432, 786432, 0, 0, 0, 4);
  };

  auto gat_layer = [&](int gi) {
    gat_att_k<<<dim3(12, 2), 256, 0, stream>>>(stb, uvec, e2all, att, gi);
    gat_g_k<<<dim3(48, 4, 2), 256, 0, stream>>>(stb, desc2db, att, obuf);
    bgemm(obuf, nullptr, 0, 256, 0, gatwT_bf + (ll)gi * 65536, nullptr, nullptr,
          stf + (ll)2 * 786432, stb + (ll)2 * 786432, nullptr, nullptr,
          256, 256, 256, 1.f, 786432, 0, 0, 0, 786432, 786432, 0, 0, 1, 2);
  };

  int ai = 0, gi = 0;
  for (int r = 0; r < 4; ++r) {
    gat_layer(gi); gi++;
    attn_layer(ai, 0); ai++;   // self
    attn_layer(ai, 1); ai++;   // cross (za=2 selects src state for k/v)
  }

  // final projection -> bf16, then row norms
  bgemm(stb, nullptr, 0, 256, 0, finw_bf, finb, nullptr, nullptr, finbf, nullptr, nullptr,
        256, 256, 256, 1.f, 786432, 0, 0, 0, 0, 786432, 0, 0, 0, 4);
  normcalc_k<<<dim3(12, 4), 256, 0, stream>>>(finbf, svec);

  // scores = 10 * norm(mq)[n] . norm(md)[m] -> conf region of d_out
  float* conf = out + 12288;
  bgemm(finbf, nullptr, 0, 256, 0, finbf, nullptr, nullptr, conf, nullptr, svec, svec,
        3072, 256, 3072, 10.f, 786432, 0, 786432, 0, 9437184, 0, 0, 2, 0, 2);

  colstat_part_k<<<dim3(12, 48, 2), 256, 0, stream>>>(conf, pmax, psum);
  colstat_comb_k<<<dim3(12, 2), 256, 0, stream>>>(pmax, psum, cmax, csum);
  rowfix_k<<<dim3(NPOS, 2), 256, 0, stream>>>(conf, cmax, csum, i0, m0);
  colamax_part_k<<<dim3(12, 24), 256, 0, stream>>>(conf, capv, capi);
  colamax_comb_k<<<12, 256, 0, stream>>>(capv, capi, i1);
  match0_k<<<12, 256, 0, stream>>>(i0, m0, i1, out);
  match1_k<<<12, 256, 0, stream>>>(i0, i1, out);
}